// Round 4
// baseline (586.805 us; speedup 1.0000x reference)
//
#include <hip/hip_runtime.h>
#include <cstdint>
#include <cstddef>

#define F_IN 128
#define HC12 256   // HEADS*HID for layers 1/2
#define HC3P 512   // padded row stride (u16) for layer-3 activations: 4 heads x 128
#define NCLS 121
#define L3STR 128  // lin3h row stride (u16)

typedef unsigned short u16;
typedef unsigned int u32;
typedef __attribute__((ext_vector_type(8))) short short8;
typedef __attribute__((ext_vector_type(8))) __fp16 half8;
typedef __attribute__((ext_vector_type(4))) float float4v;

static __device__ __forceinline__ float lrelu(float x) { return x > 0.f ? x : 0.2f * x; }

static __device__ __forceinline__ u16 f2h(float f) {
    union { __fp16 h; u16 u; } v; v.h = (__fp16)f; return v.u;
}
static __device__ __forceinline__ float h2f(u16 u) {
    union { u16 u; __fp16 h; } v; v.u = u; return (float)v.h;
}

static __device__ __forceinline__ void gload16(const u16* g, u16* l) {
    __builtin_amdgcn_global_load_lds((const __attribute__((address_space(1))) void*)g,
                                     (__attribute__((address_space(3))) void*)l,
                                     16, 0, 0);
}

// ---------------- CSR build ----------------
__global__ void hist_kernel(const int* __restrict__ dst, int* __restrict__ deg, int E) {
    int e = blockIdx.x * 256 + threadIdx.x;
    if (e < E) atomicAdd(&deg[dst[e]], 1);
}

__global__ __launch_bounds__(1024) void scan_kernel(const int* __restrict__ deg,
                                                    int* __restrict__ rowp, int N) {
    __shared__ int swave[16];
    __shared__ int s_carry;
    int tid = threadIdx.x;
    int w = tid >> 6, lane = tid & 63;
    if (tid == 0) { rowp[0] = 0; s_carry = 0; }
    __syncthreads();
    for (int base = 0; base < N; base += 4096) {
        int i0 = base + tid * 4;
        int v0 = (i0     < N) ? deg[i0]     : 0;
        int v1 = (i0 + 1 < N) ? deg[i0 + 1] : 0;
        int v2 = (i0 + 2 < N) ? deg[i0 + 2] : 0;
        int v3 = (i0 + 3 < N) ? deg[i0 + 3] : 0;
        int t = v0 + v1 + v2 + v3;
        int sc = t;
#pragma unroll
        for (int off = 1; off < 64; off <<= 1) {
            int u = __shfl_up(sc, off, 64);
            if (lane >= off) sc += u;
        }
        if (lane == 63) swave[w] = sc;
        __syncthreads();
        if (w == 0) {
            int ws = (lane < 16) ? swave[lane] : 0;
#pragma unroll
            for (int off = 1; off < 16; off <<= 1) {
                int u = __shfl_up(ws, off, 64);
                if (lane >= off) ws += u;
            }
            if (lane < 16) swave[lane] = ws;
        }
        __syncthreads();
        int carry = s_carry;
        int tb = carry + ((w > 0) ? swave[w - 1] : 0) + sc - t;
        if (i0     < N) rowp[i0 + 1] = tb + v0;
        if (i0 + 1 < N) rowp[i0 + 2] = tb + v0 + v1;
        if (i0 + 2 < N) rowp[i0 + 3] = tb + v0 + v1 + v2;
        if (i0 + 3 < N) rowp[i0 + 4] = tb + t;
        __syncthreads();
        if (tid == 1023) s_carry = carry + swave[15];
        __syncthreads();
    }
}

__global__ void scatter_kernel(const int* __restrict__ src, const int* __restrict__ dst,
                               const int* __restrict__ rowp, int* __restrict__ cur,
                               int* __restrict__ col, int E) {
    int e = blockIdx.x * 256 + threadIdx.x;
    if (e < E) {
        int d = dst[e];
        int pos = rowp[d] + atomicAdd(&cur[d], 1);
        col[pos] = src[e];
    }
}

// ---------------- fused weight transpose to f16 ----------------
__global__ void cvtT_all_kernel(const float* W1, const float* l1W, const float* W2,
                                const float* W3, const float* l3W,
                                u16* C1, u16* C2, u16* C3) {
    int i = blockIdx.x * 256 + threadIdx.x;
    const float* B; u16* o; int K, N;
    if (i < 32768)       { B = W1;  o = C1;             K = 128; N = 256; }
    else if (i < 65536)  { B = l1W; o = C1 + 256 * 128; K = 128; N = 256; i -= 32768; }
    else if (i < 131072) { B = W2;  o = C2;             K = 256; N = 256; i -= 65536; }
    else if (i < 254976) { B = W3;  o = C3;             K = 256; N = 484; i -= 131072; }
    else if (i < 285952) { B = l3W; o = C3 + 484 * 256; K = 256; N = 121; i -= 254976; }
    else return;
    int n = i % N, k = i / N;
    o[(size_t)n * K + k] = f2h(B[(size_t)k * N + n]);
}

// ---------------- x fp32 -> f16 ----------------
__global__ __launch_bounds__(256) void xcvt_kernel(const float* __restrict__ x,
                                                   u16* __restrict__ o, int total8) {
    int i = blockIdx.x * 256 + threadIdx.x;
    if (i >= total8) return;
    const float4* p = (const float4*)(x + (size_t)i * 8);
    float4 a = p[0], b = p[1];
    union { u16 u[8]; short8 v; } r;
    r.u[0] = f2h(a.x); r.u[1] = f2h(a.y); r.u[2] = f2h(a.z); r.u[3] = f2h(a.w);
    r.u[4] = f2h(b.x); r.u[5] = f2h(b.y); r.u[6] = f2h(b.z); r.u[7] = f2h(b.w);
    *(short8*)(o + (size_t)i * 8) = r.v;
}

// ---------------- f16 MFMA GEMM, 128x128 tile, global_load_lds staging ----------------
#define BM 128
#define BN 128
#define BK 32

__global__ __launch_bounds__(256, 3) void gemm_f16(const u16* __restrict__ A16,
                                                   const u16* __restrict__ BT,
                                                   int M, int K, int Ntot,
                                                   int nx, int ny,
                                                   int Nb, u16* __restrict__ Cb, int strideB,
                                                   int pad121,
                                                   u16* __restrict__ Cf16,
                                                   const float* __restrict__ biasf, int strideF) {
    __shared__ __align__(16) u16 sA[BM * BK];
    __shared__ __align__(16) u16 sB[BN * BK];
    int tid = threadIdx.x;
    int wave = tid >> 6, lane = tid & 63;
    int wr = wave >> 1, wc = wave & 1;

    // XCD-aware block swizzle
    int bid = blockIdx.x;
    int G = nx * 8;
    int g = bid / G;
    int rem = ny - g * 8;
    int rb, cb;
    if (rem >= 8) {
        int r = bid - g * G;
        rb = g * 8 + (r & 7);
        cb = r >> 3;
    } else {
        int t = bid - g * G;
        rb = g * 8 + t % rem;
        cb = t / rem;
    }
    int m0 = rb * BM, n0 = cb * BN;

    int fm = lane & 15;
    int q = lane >> 4;

    int srow = lane >> 2;
    int sch = (lane & 3) * 8;
    u16* lA0 = &sA[(wave * 32) * BK];
    u16* lA1 = &sA[(wave * 32 + 16) * BK];
    u16* lB0 = &sB[(wave * 32) * BK];
    u16* lB1 = &sB[(wave * 32 + 16) * BK];
    int ar0 = min(m0 + wave * 32 + srow, M - 1);
    int ar1 = min(m0 + wave * 32 + 16 + srow, M - 1);
    int br0 = min(n0 + wave * 32 + srow, Ntot - 1);
    int br1 = min(n0 + wave * 32 + 16 + srow, Ntot - 1);

    float4v acc[4][4];
#pragma unroll
    for (int i = 0; i < 4; i++)
#pragma unroll
        for (int j = 0; j < 4; j++) acc[i][j] = (float4v){0.f, 0.f, 0.f, 0.f};

    for (int kc = 0; kc < K; kc += BK) {
        gload16(&A16[(size_t)ar0 * K + kc + sch], lA0);
        gload16(&A16[(size_t)ar1 * K + kc + sch], lA1);
        gload16(&BT[(size_t)br0 * K + kc + sch], lB0);
        gload16(&BT[(size_t)br1 * K + kc + sch], lB1);
        __syncthreads();

        half8 ah[4];
#pragma unroll
        for (int mi = 0; mi < 4; mi++)
            ah[mi] = *(const half8*)&sA[(wr * 64 + mi * 16 + fm) * BK + q * 8];
#pragma unroll
        for (int ni = 0; ni < 4; ni++) {
            half8 bh = *(const half8*)&sB[(wc * 64 + ni * 16 + fm) * BK + q * 8];
#pragma unroll
            for (int mi = 0; mi < 4; mi++)
                acc[mi][ni] = __builtin_amdgcn_mfma_f32_16x16x32_f16(ah[mi], bh, acc[mi][ni], 0, 0, 0);
        }
        __syncthreads();
    }

#pragma unroll
    for (int mi = 0; mi < 4; mi++) {
#pragma unroll
        for (int ni = 0; ni < 4; ni++) {
            int colg = n0 + wc * 64 + ni * 16 + fm;
            if (colg >= Ntot) continue;
            int cg = colg;
            if (pad121 && colg < Nb) {
                int hh = (colg * 1084) >> 17;   // colg/121 for colg<484
                cg = colg + 7 * hh;             // head*128 + class
            }
#pragma unroll
            for (int r = 0; r < 4; r++) {
                int rowg = m0 + wr * 64 + mi * 16 + q * 4 + r;
                if (rowg >= M) continue;
                float v = acc[mi][ni][r];
                if (colg < Nb) {
                    Cb[(size_t)rowg * strideB + cg] = f2h(v);
                } else {
                    int cf = colg - Nb;
                    Cf16[(size_t)rowg * strideF + cf] = f2h(v + biasf[cf]);
                }
            }
        }
    }
}

// ---------------- wave-per-node attention coefficients, C=64 (layers 1/2) ----------------
__global__ __launch_bounds__(256) void alpha_wave_256(const u16* __restrict__ xh,
                                                      const float* __restrict__ a_s,
                                                      const float* __restrict__ a_d,
                                                      float* __restrict__ as_o,
                                                      float* __restrict__ ad_o, int N) {
    int lane = threadIdx.x & 63;
    int n = blockIdx.x * 4 + (threadIdx.x >> 6);
    if (n >= N) return;
    int c = lane * 4;
    uint2 v = *(const uint2*)&xh[(size_t)n * HC12 + c];
    float4 s4 = *(const float4*)&a_s[c];
    float4 d4 = *(const float4*)&a_d[c];
    float x0 = h2f((u16)(v.x & 0xffff)), x1 = h2f((u16)(v.x >> 16));
    float x2 = h2f((u16)(v.y & 0xffff)), x3 = h2f((u16)(v.y >> 16));
    float ss = x0 * s4.x + x1 * s4.y + x2 * s4.z + x3 * s4.w;
    float sd = x0 * d4.x + x1 * d4.y + x2 * d4.z + x3 * d4.w;
#pragma unroll
    for (int o = 1; o < 16; o <<= 1) {
        ss += __shfl_xor(ss, o, 64);
        sd += __shfl_xor(sd, o, 64);
    }
    if ((lane & 15) == 0) {
        as_o[n * 4 + (lane >> 4)] = ss;
        ad_o[n * 4 + (lane >> 4)] = sd;
    }
}

// ---------------- wave-per-node layer-3 attention coefficients (padded xh3) ----------------
// lane l: head l>>4, classes (l&15)*8..+7 via one uint4; reduce within 16-lane head group.
__global__ __launch_bounds__(256) void alpha3_wave(const u16* __restrict__ xh3,
                                                   const float* __restrict__ a_s,
                                                   const float* __restrict__ a_d,
                                                   float* __restrict__ as_o,
                                                   float* __restrict__ ad_o, int N) {
    int l = threadIdx.x & 63;
    int n = blockIdx.x * 4 + (threadIdx.x >> 6);
    if (n >= N) return;
    int h = l >> 4, li = l & 15;
    int c0 = li * 8;
    uint4 v = *(const uint4*)&xh3[(size_t)n * HC3P + l * 8];
    u32 ww[4] = {v.x, v.y, v.z, v.w};
    float ss = 0.f, sd = 0.f;
#pragma unroll
    for (int j = 0; j < 8; j++) {
        int cc = c0 + j;
        if (cc < NCLS) {
            u16 raw = (u16)((ww[j >> 1] >> ((j & 1) * 16)) & 0xffff);
            float xf = h2f(raw);
            ss += xf * a_s[h * NCLS + cc];
            sd += xf * a_d[h * NCLS + cc];
        }
    }
#pragma unroll
    for (int o = 1; o < 16; o <<= 1) {
        ss += __shfl_xor(ss, o, 64);
        sd += __shfl_xor(sd, o, 64);
    }
    if (li == 0) {
        as_o[n * 4 + h] = ss;
        ad_o[n * 4 + h] = sd;
    }
}

// ---------------- fused softmax stats + per-edge alpha ----------------
__global__ __launch_bounds__(256) void stats_alpha_kernel(const int* __restrict__ rowp,
                                                          const int* __restrict__ col,
                                                          const float* __restrict__ asrc,
                                                          const float* __restrict__ adst,
                                                          float* __restrict__ alphaE, int N) {
    int i = blockIdx.x * 256 + threadIdx.x;
    if (i >= N * 4) return;
    int n = i >> 2, h = i & 3;
    int r0 = rowp[n], r1 = rowp[n + 1];
    float ad = adst[i];
    float m = -3.4e38f, s = 0.f;
    for (int e = r0; e < r1; e++) {
        int sc = col[e];
        float l = lrelu(asrc[sc * 4 + h] + ad);
        float nm = fmaxf(m, l);
        s = s * __expf(m - nm) + __expf(l - nm);
        m = nm;
    }
    float rd = 1.f / (s + 1e-16f);
    for (int e = r0; e < r1; e++) {
        int sc = col[e];
        float l = lrelu(asrc[sc * 4 + h] + ad);
        alphaE[(size_t)e * 4 + h] = __expf(l - m) * rd;
    }
}

// ---------------- wave-per-node aggregate, HC=256, 2 edges/iteration ----------------
// lanes split into 2 edge-slots x 32 lanes; lane owns 8 channels (uint4).
// res16: f16 residual/lin input; out16: f16 activated output.
__global__ __launch_bounds__(256) void agg_wave_256(const u16* __restrict__ xh,
                                                    const int* __restrict__ rowp,
                                                    const int* __restrict__ col,
                                                    const float* __restrict__ alphaE,
                                                    const float* __restrict__ bias,
                                                    const u16* __restrict__ res16,
                                                    u16* __restrict__ out16, int N) {
    int l = threadIdx.x & 63;
    int n = blockIdx.x * 4 + (threadIdx.x >> 6);
    if (n >= N) return;
    int r0 = rowp[n], r1 = rowp[n + 1];
    int s = l >> 5, li = l & 31;
    int c = li * 8;
    int h = li >> 3;
    float acc[8] = {0.f, 0.f, 0.f, 0.f, 0.f, 0.f, 0.f, 0.f};
    for (int kb = r0; kb < r1; kb += 16) {
        int cn = min(16, r1 - kb);
        int cidx = col[kb + (l & 15)];
        float alv = alphaE[(size_t)kb * 4 + l];
        int npair = (cn + 1) >> 1;
#pragma unroll 4
        for (int k = 0; k < npair; k++) {
            int e = 2 * k + s;
            int em = e < cn ? e : cn - 1;
            int src = __shfl(cidx, em, 64);
            float al = __shfl(alv, em * 4 + h, 64);
            if (e >= cn) al = 0.f;
            uint4 v = *(const uint4*)&xh[(size_t)src * HC12 + c];
            acc[0] += al * h2f((u16)(v.x & 0xffff));
            acc[1] += al * h2f((u16)(v.x >> 16));
            acc[2] += al * h2f((u16)(v.y & 0xffff));
            acc[3] += al * h2f((u16)(v.y >> 16));
            acc[4] += al * h2f((u16)(v.z & 0xffff));
            acc[5] += al * h2f((u16)(v.z >> 16));
            acc[6] += al * h2f((u16)(v.w & 0xffff));
            acc[7] += al * h2f((u16)(v.w >> 16));
        }
    }
#pragma unroll
    for (int j = 0; j < 8; j++) acc[j] += __shfl_xor(acc[j], 32, 64);
    if (l < 32) {
        uint4 rv = *(const uint4*)&res16[(size_t)n * HC12 + c];
        u32 rw[4] = {rv.x, rv.y, rv.z, rv.w};
        float4 b0 = *(const float4*)&bias[c];
        float4 b1v = *(const float4*)&bias[c + 4];
        float bb[8] = {b0.x, b0.y, b0.z, b0.w, b1v.x, b1v.y, b1v.z, b1v.w};
        union { u16 u[8]; uint4 v; } p;
#pragma unroll
        for (int j = 0; j < 8; j++) {
            float rf = h2f((u16)((rw[j >> 1] >> ((j & 1) * 16)) & 0xffff));
            float vv = acc[j] + bb[j] + rf;
            float ev = vv > 0.f ? vv : expm1f(vv);
            p.u[j] = f2h(ev);
        }
        *(uint4*)&out16[(size_t)n * HC12 + c] = p.v;
    }
}

// ---------------- wave-per-node layer-3 aggregate (padded 1024B rows, 1 uint4/lane) ----------------
__global__ __launch_bounds__(256) void agg_wave_out(const u16* __restrict__ xh3,
                                                    const int* __restrict__ rowp,
                                                    const int* __restrict__ col,
                                                    const float* __restrict__ alphaE,
                                                    const float* __restrict__ b3,
                                                    const u16* __restrict__ lin3h,
                                                    float* __restrict__ out, int N) {
    int l = threadIdx.x & 63;
    int n = blockIdx.x * 4 + (threadIdx.x >> 6);
    if (n >= N) return;
    int r0 = rowp[n], r1 = rowp[n + 1];
    int h = l >> 4;
    float acc[8] = {0.f, 0.f, 0.f, 0.f, 0.f, 0.f, 0.f, 0.f};
    for (int kb = r0; kb < r1; kb += 16) {
        int cn = min(16, r1 - kb);
        int cidx = col[kb + (l & 15)];
        float alv = alphaE[(size_t)kb * 4 + l];
#pragma unroll 4
        for (int k = 0; k < cn; k++) {
            int src = __shfl(cidx, k, 64);
            float al = __shfl(alv, k * 4 + h, 64);
            uint4 v = *(const uint4*)&xh3[(size_t)src * HC3P + l * 8];
            acc[0] += al * h2f((u16)(v.x & 0xffff));
            acc[1] += al * h2f((u16)(v.x >> 16));
            acc[2] += al * h2f((u16)(v.y & 0xffff));
            acc[3] += al * h2f((u16)(v.y >> 16));
            acc[4] += al * h2f((u16)(v.z & 0xffff));
            acc[5] += al * h2f((u16)(v.z >> 16));
            acc[6] += al * h2f((u16)(v.w & 0xffff));
            acc[7] += al * h2f((u16)(v.w >> 16));
        }
    }
#pragma unroll
    for (int j = 0; j < 8; j++) {
        acc[j] += __shfl_xor(acc[j], 16, 64);
        acc[j] += __shfl_xor(acc[j], 32, 64);
    }
    if (l < 16) {
        uint4 lv = *(const uint4*)&lin3h[(size_t)n * L3STR + l * 8];
        u32 lw[4] = {lv.x, lv.y, lv.z, lv.w};
        int c0 = l * 8;
#pragma unroll
        for (int j = 0; j < 8; j++) {
            int cc = c0 + j;
            if (cc < NCLS) {
                float lf = h2f((u16)((lw[j >> 1] >> ((j & 1) * 16)) & 0xffff));
                out[(size_t)n * NCLS + cc] = 0.25f * acc[j] + b3[cc] + lf;
            }
        }
    }
}

extern "C" void kernel_launch(void* const* d_in, const int* in_sizes, int n_in,
                              void* d_out, int out_size, void* d_ws, size_t ws_size,
                              hipStream_t stream) {
    const float* x   = (const float*)d_in[0];
    const int*   ei  = (const int*)d_in[1];
    const float* W1  = (const float*)d_in[2];
    const float* a1s = (const float*)d_in[3];
    const float* a1d = (const float*)d_in[4];
    const float* b1  = (const float*)d_in[5];
    const float* l1W = (const float*)d_in[6];
    const float* l1b = (const float*)d_in[7];
    const float* W2  = (const float*)d_in[8];
    const float* a2s = (const float*)d_in[9];
    const float* a2d = (const float*)d_in[10];
    const float* b2  = (const float*)d_in[11];
    const float* W3  = (const float*)d_in[12];
    const float* a3s = (const float*)d_in[13];
    const float* a3d = (const float*)d_in[14];
    const float* b3  = (const float*)d_in[15];
    const float* l3W = (const float*)d_in[16];
    const float* l3b = (const float*)d_in[17];

    const int N = in_sizes[0] / F_IN;   // 50000
    const int E = in_sizes[1] / 2;      // 400000
    const int* srcv = ei;
    const int* dstv = ei + E;

    char* ws = (char*)d_ws;
    size_t off = 0;
    auto alloc = [&](size_t bytes) -> char* {
        char* p = ws + off;
        off += (bytes + 255) & ~(size_t)255;
        return p;
    };
    u16*   xh    = (u16*)alloc((size_t)N * HC3P * 2 + 256);
    u16*   x16   = (u16*)alloc((size_t)N * F_IN * 2);
    u16*   h1f   = (u16*)alloc((size_t)N * HC12 * 2);
    u16*   h2f   = (u16*)alloc((size_t)N * HC12 * 2);
    u16*   lin1h = (u16*)alloc((size_t)N * HC12 * 2);
    u16*   lin3h = (u16*)alloc((size_t)N * L3STR * 2);
    float* as_   = (float*)alloc((size_t)N * 4 * 4);
    float* ad_   = (float*)alloc((size_t)N * 4 * 4);
    int* rowp    = (int*)alloc((size_t)(N + 1) * 4);
    int* degc    = (int*)alloc((size_t)N * 4);
    int* cur     = (int*)alloc((size_t)N * 4);
    int* col     = (int*)alloc((size_t)E * 4 + 256);
    float* alphaE = (float*)alloc((size_t)E * 4 * 4 + 256);
    u16* C1 = (u16*)alloc((size_t)512 * 128 * 2);
    u16* C2 = (u16*)alloc((size_t)256 * 256 * 2);
    u16* C3 = (u16*)alloc((size_t)605 * 256 * 2);
    (void)ws_size; (void)n_in; (void)out_size;

    // ---- CSR build ----
    hipMemsetAsync(degc, 0, (size_t)N * 4, stream);
    hipMemsetAsync(cur, 0, (size_t)N * 4, stream);
    hist_kernel<<<(E + 255) / 256, 256, 0, stream>>>(dstv, degc, E);
    scan_kernel<<<1, 1024, 0, stream>>>(degc, rowp, N);
    scatter_kernel<<<(E + 255) / 256, 256, 0, stream>>>(srcv, dstv, rowp, cur, col, E);

    // ---- weight transpose + x conversion ----
    cvtT_all_kernel<<<(285952 + 255) / 256, 256, 0, stream>>>(W1, l1W, W2, W3, l3W, C1, C2, C3);
    xcvt_kernel<<<(N * F_IN / 8 + 255) / 256, 256, 0, stream>>>(x, x16, N * F_IN / 8);

    int ny = (N + BM - 1) / BM;
    int sgrid = (N * 4 + 255) / 256;
    int wgrid = (N + 3) / 4;

    // ---- layer 1: one GEMM, N=512 (cols 0-255 -> xh f16, 256-511 -> lin1h f16 + l1b) ----
    gemm_f16<<<4 * ny, 256, 0, stream>>>(x16, C1, N, F_IN, 512, 4, ny,
                                         256, xh, 256, 0, lin1h, l1b, 256);
    alpha_wave_256<<<wgrid, 256, 0, stream>>>(xh, a1s, a1d, as_, ad_, N);
    stats_alpha_kernel<<<sgrid, 256, 0, stream>>>(rowp, col, as_, ad_, alphaE, N);
    agg_wave_256<<<wgrid, 256, 0, stream>>>(xh, rowp, col, alphaE, b1, lin1h, h1f, N);

    // ---- layer 2: N=256, residual = h1f ----
    gemm_f16<<<2 * ny, 256, 0, stream>>>(h1f, C2, N, HC12, 256, 2, ny,
                                         256, xh, 256, 0, nullptr, nullptr, 0);
    alpha_wave_256<<<wgrid, 256, 0, stream>>>(xh, a2s, a2d, as_, ad_, N);
    stats_alpha_kernel<<<sgrid, 256, 0, stream>>>(rowp, col, as_, ad_, alphaE, N);
    agg_wave_256<<<wgrid, 256, 0, stream>>>(xh, rowp, col, alphaE, b2, h1f, h2f, N);

    // ---- layer 3: one GEMM, N=605, padded xh3 (stride 512), cols 484-604 -> lin3h f16 + l3b ----
    gemm_f16<<<5 * ny, 256, 0, stream>>>(h2f, C3, N, HC12, 605, 5, ny,
                                         484, xh, HC3P, 1, lin3h, l3b, L3STR);
    alpha3_wave<<<wgrid, 256, 0, stream>>>(xh, a3s, a3d, as_, ad_, N);
    stats_alpha_kernel<<<sgrid, 256, 0, stream>>>(rowp, col, as_, ad_, alphaE, N);
    agg_wave_out<<<wgrid, 256, 0, stream>>>(xh, rowp, col, alphaE, b3, lin3h, (float*)d_out, N);
}

// Round 5
// 507.409 us; speedup vs baseline: 1.1565x; 1.1565x over previous
//
#include <hip/hip_runtime.h>
#include <cstdint>
#include <cstddef>

#define F_IN 128
#define HC12 256   // HEADS*HID for layers 1/2
#define HC3P 512   // padded row stride (u16) for layer-3 activations: 4 heads x 128
#define NCLS 121
#define L3STR 128  // lin3h row stride (u16)

typedef unsigned short u16;
typedef unsigned int u32;
typedef __attribute__((ext_vector_type(8))) short short8;
typedef __attribute__((ext_vector_type(8))) __fp16 half8;
typedef __attribute__((ext_vector_type(4))) float float4v;

static __device__ __forceinline__ float lrelu(float x) { return x > 0.f ? x : 0.2f * x; }

static __device__ __forceinline__ u16 f2h(float f) {
    union { __fp16 h; u16 u; } v; v.h = (__fp16)f; return v.u;
}
static __device__ __forceinline__ float h2f(u16 u) {
    union { u16 u; __fp16 h; } v; v.u = u; return (float)v.h;
}

static __device__ __forceinline__ void gload16(const u16* g, u16* l) {
    __builtin_amdgcn_global_load_lds((const __attribute__((address_space(1))) void*)g,
                                     (__attribute__((address_space(3))) void*)l,
                                     16, 0, 0);
}

// ---------------- CSR build ----------------
__global__ void hist_kernel(const int* __restrict__ dst, int* __restrict__ deg, int E) {
    int e = blockIdx.x * 256 + threadIdx.x;
    if (e < E) atomicAdd(&deg[dst[e]], 1);
}

__global__ __launch_bounds__(1024) void scan_kernel(const int* __restrict__ deg,
                                                    int* __restrict__ rowp, int N) {
    __shared__ int swave[16];
    __shared__ int s_carry;
    int tid = threadIdx.x;
    int w = tid >> 6, lane = tid & 63;
    if (tid == 0) { rowp[0] = 0; s_carry = 0; }
    __syncthreads();
    for (int base = 0; base < N; base += 4096) {
        int i0 = base + tid * 4;
        int v0 = (i0     < N) ? deg[i0]     : 0;
        int v1 = (i0 + 1 < N) ? deg[i0 + 1] : 0;
        int v2 = (i0 + 2 < N) ? deg[i0 + 2] : 0;
        int v3 = (i0 + 3 < N) ? deg[i0 + 3] : 0;
        int t = v0 + v1 + v2 + v3;
        int sc = t;
#pragma unroll
        for (int off = 1; off < 64; off <<= 1) {
            int u = __shfl_up(sc, off, 64);
            if (lane >= off) sc += u;
        }
        if (lane == 63) swave[w] = sc;
        __syncthreads();
        if (w == 0) {
            int ws = (lane < 16) ? swave[lane] : 0;
#pragma unroll
            for (int off = 1; off < 16; off <<= 1) {
                int u = __shfl_up(ws, off, 64);
                if (lane >= off) ws += u;
            }
            if (lane < 16) swave[lane] = ws;
        }
        __syncthreads();
        int carry = s_carry;
        int tb = carry + ((w > 0) ? swave[w - 1] : 0) + sc - t;
        if (i0     < N) rowp[i0 + 1] = tb + v0;
        if (i0 + 1 < N) rowp[i0 + 2] = tb + v0 + v1;
        if (i0 + 2 < N) rowp[i0 + 3] = tb + v0 + v1 + v2;
        if (i0 + 3 < N) rowp[i0 + 4] = tb + t;
        __syncthreads();
        if (tid == 1023) s_carry = carry + swave[15];
        __syncthreads();
    }
}

__global__ void scatter_kernel(const int* __restrict__ src, const int* __restrict__ dst,
                               const int* __restrict__ rowp, int* __restrict__ cur,
                               int* __restrict__ col, int E) {
    int e = blockIdx.x * 256 + threadIdx.x;
    if (e < E) {
        int d = dst[e];
        int pos = rowp[d] + atomicAdd(&cur[d], 1);
        col[pos] = src[e];
    }
}

// ---------------- fused weight transpose to f16 (+ padded a3 tables) ----------------
__global__ void cvtT_all_kernel(const float* W1, const float* l1W, const float* W2,
                                const float* W3, const float* l3W,
                                const float* a3s, const float* a3d,
                                u16* C1, u16* C2, u16* C3,
                                float* as3p, float* ad3p) {
    int i = blockIdx.x * 256 + threadIdx.x;
    if (i >= 285952) {
        int j = i - 285952;
        if (j < 1024) {
            int t = j >> 9, k = j & 511;
            int h = k >> 7, c = k & 127;
            const float* a = t ? a3d : a3s;
            float v = (c < NCLS) ? a[h * NCLS + c] : 0.f;
            (t ? ad3p : as3p)[k] = v;
        }
        return;
    }
    const float* B; u16* o; int K, N;
    if (i < 32768)       { B = W1;  o = C1;             K = 128; N = 256; }
    else if (i < 65536)  { B = l1W; o = C1 + 256 * 128; K = 128; N = 256; i -= 32768; }
    else if (i < 131072) { B = W2;  o = C2;             K = 256; N = 256; i -= 65536; }
    else if (i < 254976) { B = W3;  o = C3;             K = 256; N = 484; i -= 131072; }
    else                 { B = l3W; o = C3 + 484 * 256; K = 256; N = 121; i -= 254976; }
    int n = i % N, k = i / N;
    o[(size_t)n * K + k] = f2h(B[(size_t)k * N + n]);
}

// ---------------- x fp32 -> f16 ----------------
__global__ __launch_bounds__(256) void xcvt_kernel(const float* __restrict__ x,
                                                   u16* __restrict__ o, int total8) {
    int i = blockIdx.x * 256 + threadIdx.x;
    if (i >= total8) return;
    const float4* p = (const float4*)(x + (size_t)i * 8);
    float4 a = p[0], b = p[1];
    union { u16 u[8]; short8 v; } r;
    r.u[0] = f2h(a.x); r.u[1] = f2h(a.y); r.u[2] = f2h(a.z); r.u[3] = f2h(a.w);
    r.u[4] = f2h(b.x); r.u[5] = f2h(b.y); r.u[6] = f2h(b.z); r.u[7] = f2h(b.w);
    *(short8*)(o + (size_t)i * 8) = r.v;
}

// ---------------- f16 MFMA GEMM, 128x128 tile, global_load_lds staging ----------------
#define BM 128
#define BN 128
#define BK 32

__global__ __launch_bounds__(256, 3) void gemm_f16(const u16* __restrict__ A16,
                                                   const u16* __restrict__ BT,
                                                   int M, int K, int Ntot,
                                                   int nx, int ny,
                                                   int Nb, u16* __restrict__ Cb, int strideB,
                                                   int pad121,
                                                   u16* __restrict__ Cf16,
                                                   const float* __restrict__ biasf, int strideF) {
    __shared__ __align__(16) u16 sA[BM * BK];
    __shared__ __align__(16) u16 sB[BN * BK];
    int tid = threadIdx.x;
    int wave = tid >> 6, lane = tid & 63;
    int wr = wave >> 1, wc = wave & 1;

    // XCD-aware block swizzle
    int bid = blockIdx.x;
    int G = nx * 8;
    int g = bid / G;
    int rem = ny - g * 8;
    int rb, cb;
    if (rem >= 8) {
        int r = bid - g * G;
        rb = g * 8 + (r & 7);
        cb = r >> 3;
    } else {
        int t = bid - g * G;
        rb = g * 8 + t % rem;
        cb = t / rem;
    }
    int m0 = rb * BM, n0 = cb * BN;

    int fm = lane & 15;
    int q = lane >> 4;

    int srow = lane >> 2;
    int sch = (lane & 3) * 8;
    u16* lA0 = &sA[(wave * 32) * BK];
    u16* lA1 = &sA[(wave * 32 + 16) * BK];
    u16* lB0 = &sB[(wave * 32) * BK];
    u16* lB1 = &sB[(wave * 32 + 16) * BK];
    int ar0 = min(m0 + wave * 32 + srow, M - 1);
    int ar1 = min(m0 + wave * 32 + 16 + srow, M - 1);
    int br0 = min(n0 + wave * 32 + srow, Ntot - 1);
    int br1 = min(n0 + wave * 32 + 16 + srow, Ntot - 1);

    float4v acc[4][4];
#pragma unroll
    for (int i = 0; i < 4; i++)
#pragma unroll
        for (int j = 0; j < 4; j++) acc[i][j] = (float4v){0.f, 0.f, 0.f, 0.f};

    for (int kc = 0; kc < K; kc += BK) {
        gload16(&A16[(size_t)ar0 * K + kc + sch], lA0);
        gload16(&A16[(size_t)ar1 * K + kc + sch], lA1);
        gload16(&BT[(size_t)br0 * K + kc + sch], lB0);
        gload16(&BT[(size_t)br1 * K + kc + sch], lB1);
        __syncthreads();

        half8 ah[4];
#pragma unroll
        for (int mi = 0; mi < 4; mi++)
            ah[mi] = *(const half8*)&sA[(wr * 64 + mi * 16 + fm) * BK + q * 8];
#pragma unroll
        for (int ni = 0; ni < 4; ni++) {
            half8 bh = *(const half8*)&sB[(wc * 64 + ni * 16 + fm) * BK + q * 8];
#pragma unroll
            for (int mi = 0; mi < 4; mi++)
                acc[mi][ni] = __builtin_amdgcn_mfma_f32_16x16x32_f16(ah[mi], bh, acc[mi][ni], 0, 0, 0);
        }
        __syncthreads();
    }

#pragma unroll
    for (int mi = 0; mi < 4; mi++) {
#pragma unroll
        for (int ni = 0; ni < 4; ni++) {
            int colg = n0 + wc * 64 + ni * 16 + fm;
            if (colg >= Ntot) continue;
            int cg = colg;
            if (pad121 && colg < Nb) {
                int hh = (colg * 1084) >> 17;   // colg/121 for colg<484
                cg = colg + 7 * hh;             // head*128 + class
            }
#pragma unroll
            for (int r = 0; r < 4; r++) {
                int rowg = m0 + wr * 64 + mi * 16 + q * 4 + r;
                if (rowg >= M) continue;
                float v = acc[mi][ni][r];
                if (colg < Nb) {
                    Cb[(size_t)rowg * strideB + cg] = f2h(v);
                } else {
                    int cf = colg - Nb;
                    Cf16[(size_t)rowg * strideF + cf] = f2h(v + biasf[cf]);
                }
            }
        }
    }
}

// ---------------- wave-per-node attention coefficients, C=64 (layers 1/2) ----------------
__global__ __launch_bounds__(256) void alpha_wave_256(const u16* __restrict__ xh,
                                                      const float* __restrict__ a_s,
                                                      const float* __restrict__ a_d,
                                                      float* __restrict__ as_o,
                                                      float* __restrict__ ad_o, int N) {
    int lane = threadIdx.x & 63;
    int n = blockIdx.x * 4 + (threadIdx.x >> 6);
    if (n >= N) return;
    int c = lane * 4;
    uint2 v = *(const uint2*)&xh[(size_t)n * HC12 + c];
    float4 s4 = *(const float4*)&a_s[c];
    float4 d4 = *(const float4*)&a_d[c];
    float x0 = h2f((u16)(v.x & 0xffff)), x1 = h2f((u16)(v.x >> 16));
    float x2 = h2f((u16)(v.y & 0xffff)), x3 = h2f((u16)(v.y >> 16));
    float ss = x0 * s4.x + x1 * s4.y + x2 * s4.z + x3 * s4.w;
    float sd = x0 * d4.x + x1 * d4.y + x2 * d4.z + x3 * d4.w;
#pragma unroll
    for (int o = 1; o < 16; o <<= 1) {
        ss += __shfl_xor(ss, o, 64);
        sd += __shfl_xor(sd, o, 64);
    }
    if ((lane & 15) == 0) {
        as_o[n * 4 + (lane >> 4)] = ss;
        ad_o[n * 4 + (lane >> 4)] = sd;
    }
}

// ---------------- wave-per-node layer-3 attention coefficients (padded, vectorized) ----------------
// lane l: head l>>4, classes (l&15)*8..+7. xh3 uint4 + 4x float4 padded-table loads,
// all unconditional & independent; pad garbage masked with cndmask (not multiply -- NaN safety).
__global__ __launch_bounds__(256) void alpha3_wave(const u16* __restrict__ xh3,
                                                   const float* __restrict__ as3p,
                                                   const float* __restrict__ ad3p,
                                                   float* __restrict__ as_o,
                                                   float* __restrict__ ad_o, int N) {
    int l = threadIdx.x & 63;
    int n = blockIdx.x * 4 + (threadIdx.x >> 6);
    if (n >= N) return;
    int h = l >> 4, li = l & 15;
    int c0 = li * 8;
    uint4 v = *(const uint4*)&xh3[(size_t)n * HC3P + l * 8];
    float4 s0 = *(const float4*)&as3p[l * 8];
    float4 s1 = *(const float4*)&as3p[l * 8 + 4];
    float4 d0 = *(const float4*)&ad3p[l * 8];
    float4 d1 = *(const float4*)&ad3p[l * 8 + 4];
    u32 ww[4] = {v.x, v.y, v.z, v.w};
    float xs[8];
#pragma unroll
    for (int j = 0; j < 8; j++) {
        float xf = h2f((u16)((ww[j >> 1] >> ((j & 1) * 16)) & 0xffff));
        xs[j] = (c0 + j < NCLS) ? xf : 0.f;   // mask pad garbage (could be NaN)
    }
    float ss = xs[0] * s0.x + xs[1] * s0.y + xs[2] * s0.z + xs[3] * s0.w
             + xs[4] * s1.x + xs[5] * s1.y + xs[6] * s1.z + xs[7] * s1.w;
    float sd = xs[0] * d0.x + xs[1] * d0.y + xs[2] * d0.z + xs[3] * d0.w
             + xs[4] * d1.x + xs[5] * d1.y + xs[6] * d1.z + xs[7] * d1.w;
#pragma unroll
    for (int o = 1; o < 16; o <<= 1) {
        ss += __shfl_xor(ss, o, 64);
        sd += __shfl_xor(sd, o, 64);
    }
    if (li == 0) {
        as_o[n * 4 + h] = ss;
        ad_o[n * 4 + h] = sd;
    }
}

// ---------------- fused softmax stats + per-edge alpha ----------------
__global__ __launch_bounds__(256) void stats_alpha_kernel(const int* __restrict__ rowp,
                                                          const int* __restrict__ col,
                                                          const float* __restrict__ asrc,
                                                          const float* __restrict__ adst,
                                                          float* __restrict__ alphaE, int N) {
    int i = blockIdx.x * 256 + threadIdx.x;
    if (i >= N * 4) return;
    int n = i >> 2, h = i & 3;
    int r0 = rowp[n], r1 = rowp[n + 1];
    float ad = adst[i];
    float m = -3.4e38f, s = 0.f;
    for (int e = r0; e < r1; e++) {
        int sc = col[e];
        float l = lrelu(asrc[sc * 4 + h] + ad);
        float nm = fmaxf(m, l);
        s = s * __expf(m - nm) + __expf(l - nm);
        m = nm;
    }
    float rd = 1.f / (s + 1e-16f);
    for (int e = r0; e < r1; e++) {
        int sc = col[e];
        float l = lrelu(asrc[sc * 4 + h] + ad);
        alphaE[(size_t)e * 4 + h] = __expf(l - m) * rd;
    }
}

// ---------------- wave-per-node aggregate, HC=256, 2 edges/iteration ----------------
__global__ __launch_bounds__(256) void agg_wave_256(const u16* __restrict__ xh,
                                                    const int* __restrict__ rowp,
                                                    const int* __restrict__ col,
                                                    const float* __restrict__ alphaE,
                                                    const float* __restrict__ bias,
                                                    const u16* __restrict__ res16,
                                                    u16* __restrict__ out16, int N) {
    int l = threadIdx.x & 63;
    int n = blockIdx.x * 4 + (threadIdx.x >> 6);
    if (n >= N) return;
    int r0 = rowp[n], r1 = rowp[n + 1];
    int s = l >> 5, li = l & 31;
    int c = li * 8;
    int h = li >> 3;
    float acc[8] = {0.f, 0.f, 0.f, 0.f, 0.f, 0.f, 0.f, 0.f};
    for (int kb = r0; kb < r1; kb += 16) {
        int cn = min(16, r1 - kb);
        int cidx = col[kb + (l & 15)];
        float alv = alphaE[(size_t)kb * 4 + l];
        int npair = (cn + 1) >> 1;
#pragma unroll 4
        for (int k = 0; k < npair; k++) {
            int e = 2 * k + s;
            int em = e < cn ? e : cn - 1;
            int src = __shfl(cidx, em, 64);
            float al = __shfl(alv, em * 4 + h, 64);
            if (e >= cn) al = 0.f;
            uint4 v = *(const uint4*)&xh[(size_t)src * HC12 + c];
            acc[0] += al * h2f((u16)(v.x & 0xffff));
            acc[1] += al * h2f((u16)(v.x >> 16));
            acc[2] += al * h2f((u16)(v.y & 0xffff));
            acc[3] += al * h2f((u16)(v.y >> 16));
            acc[4] += al * h2f((u16)(v.z & 0xffff));
            acc[5] += al * h2f((u16)(v.z >> 16));
            acc[6] += al * h2f((u16)(v.w & 0xffff));
            acc[7] += al * h2f((u16)(v.w >> 16));
        }
    }
#pragma unroll
    for (int j = 0; j < 8; j++) acc[j] += __shfl_xor(acc[j], 32, 64);
    if (l < 32) {
        uint4 rv = *(const uint4*)&res16[(size_t)n * HC12 + c];
        u32 rw[4] = {rv.x, rv.y, rv.z, rv.w};
        float4 b0 = *(const float4*)&bias[c];
        float4 b1v = *(const float4*)&bias[c + 4];
        float bb[8] = {b0.x, b0.y, b0.z, b0.w, b1v.x, b1v.y, b1v.z, b1v.w};
        union { u16 u[8]; uint4 v; } p;
#pragma unroll
        for (int j = 0; j < 8; j++) {
            float rf = h2f((u16)((rw[j >> 1] >> ((j & 1) * 16)) & 0xffff));
            float vv = acc[j] + bb[j] + rf;
            float ev = vv > 0.f ? vv : expm1f(vv);
            p.u[j] = f2h(ev);
        }
        *(uint4*)&out16[(size_t)n * HC12 + c] = p.v;
    }
}

// ---------------- wave-per-node layer-3 aggregate (padded 1024B rows, 1 uint4/lane) ----------------
__global__ __launch_bounds__(256) void agg_wave_out(const u16* __restrict__ xh3,
                                                    const int* __restrict__ rowp,
                                                    const int* __restrict__ col,
                                                    const float* __restrict__ alphaE,
                                                    const float* __restrict__ b3,
                                                    const u16* __restrict__ lin3h,
                                                    float* __restrict__ out, int N) {
    int l = threadIdx.x & 63;
    int n = blockIdx.x * 4 + (threadIdx.x >> 6);
    if (n >= N) return;
    int r0 = rowp[n], r1 = rowp[n + 1];
    int h = l >> 4;
    float acc[8] = {0.f, 0.f, 0.f, 0.f, 0.f, 0.f, 0.f, 0.f};
    for (int kb = r0; kb < r1; kb += 16) {
        int cn = min(16, r1 - kb);
        int cidx = col[kb + (l & 15)];
        float alv = alphaE[(size_t)kb * 4 + l];
#pragma unroll 4
        for (int k = 0; k < cn; k++) {
            int src = __shfl(cidx, k, 64);
            float al = __shfl(alv, k * 4 + h, 64);
            uint4 v = *(const uint4*)&xh3[(size_t)src * HC3P + l * 8];
            acc[0] += al * h2f((u16)(v.x & 0xffff));
            acc[1] += al * h2f((u16)(v.x >> 16));
            acc[2] += al * h2f((u16)(v.y & 0xffff));
            acc[3] += al * h2f((u16)(v.y >> 16));
            acc[4] += al * h2f((u16)(v.z & 0xffff));
            acc[5] += al * h2f((u16)(v.z >> 16));
            acc[6] += al * h2f((u16)(v.w & 0xffff));
            acc[7] += al * h2f((u16)(v.w >> 16));
        }
    }
#pragma unroll
    for (int j = 0; j < 8; j++) {
        acc[j] += __shfl_xor(acc[j], 16, 64);
        acc[j] += __shfl_xor(acc[j], 32, 64);
    }
    if (l < 16) {
        uint4 lv = *(const uint4*)&lin3h[(size_t)n * L3STR + l * 8];
        u32 lw[4] = {lv.x, lv.y, lv.z, lv.w};
        int c0 = l * 8;
#pragma unroll
        for (int j = 0; j < 8; j++) {
            int cc = c0 + j;
            if (cc < NCLS) {
                float lf = h2f((u16)((lw[j >> 1] >> ((j & 1) * 16)) & 0xffff));
                out[(size_t)n * NCLS + cc] = 0.25f * acc[j] + b3[cc] + lf;
            }
        }
    }
}

extern "C" void kernel_launch(void* const* d_in, const int* in_sizes, int n_in,
                              void* d_out, int out_size, void* d_ws, size_t ws_size,
                              hipStream_t stream) {
    const float* x   = (const float*)d_in[0];
    const int*   ei  = (const int*)d_in[1];
    const float* W1  = (const float*)d_in[2];
    const float* a1s = (const float*)d_in[3];
    const float* a1d = (const float*)d_in[4];
    const float* b1  = (const float*)d_in[5];
    const float* l1W = (const float*)d_in[6];
    const float* l1b = (const float*)d_in[7];
    const float* W2  = (const float*)d_in[8];
    const float* a2s = (const float*)d_in[9];
    const float* a2d = (const float*)d_in[10];
    const float* b2  = (const float*)d_in[11];
    const float* W3  = (const float*)d_in[12];
    const float* a3s = (const float*)d_in[13];
    const float* a3d = (const float*)d_in[14];
    const float* b3  = (const float*)d_in[15];
    const float* l3W = (const float*)d_in[16];
    const float* l3b = (const float*)d_in[17];

    const int N = in_sizes[0] / F_IN;   // 50000
    const int E = in_sizes[1] / 2;      // 400000
    const int* srcv = ei;
    const int* dstv = ei + E;

    char* ws = (char*)d_ws;
    size_t off = 0;
    auto alloc = [&](size_t bytes) -> char* {
        char* p = ws + off;
        off += (bytes + 255) & ~(size_t)255;
        return p;
    };
    u16*   xh    = (u16*)alloc((size_t)N * HC3P * 2 + 256);
    u16*   x16   = (u16*)alloc((size_t)N * F_IN * 2);
    u16*   h1f   = (u16*)alloc((size_t)N * HC12 * 2);
    u16*   h2f   = (u16*)alloc((size_t)N * HC12 * 2);
    u16*   lin1h = (u16*)alloc((size_t)N * HC12 * 2);
    u16*   lin3h = (u16*)alloc((size_t)N * L3STR * 2);
    float* as_   = (float*)alloc((size_t)N * 4 * 4);
    float* ad_   = (float*)alloc((size_t)N * 4 * 4);
    int* rowp    = (int*)alloc((size_t)(N + 1) * 4);
    int* degc    = (int*)alloc((size_t)N * 4);
    int* cur     = (int*)alloc((size_t)N * 4);
    int* col     = (int*)alloc((size_t)E * 4 + 256);
    float* alphaE = (float*)alloc((size_t)E * 4 * 4 + 256);
    u16* C1 = (u16*)alloc((size_t)512 * 128 * 2);
    u16* C2 = (u16*)alloc((size_t)256 * 256 * 2);
    u16* C3 = (u16*)alloc((size_t)605 * 256 * 2);
    float* as3p = (float*)alloc(512 * 4);
    float* ad3p = (float*)alloc(512 * 4);
    (void)ws_size; (void)n_in; (void)out_size;

    // ---- CSR build ----
    hipMemsetAsync(degc, 0, (size_t)N * 4, stream);
    hipMemsetAsync(cur, 0, (size_t)N * 4, stream);
    hist_kernel<<<(E + 255) / 256, 256, 0, stream>>>(dstv, degc, E);
    scan_kernel<<<1, 1024, 0, stream>>>(degc, rowp, N);
    scatter_kernel<<<(E + 255) / 256, 256, 0, stream>>>(srcv, dstv, rowp, cur, col, E);

    // ---- weight transpose + x conversion + padded a3 tables ----
    cvtT_all_kernel<<<(285952 + 1024 + 255) / 256, 256, 0, stream>>>(W1, l1W, W2, W3, l3W,
                                                                     a3s, a3d, C1, C2, C3,
                                                                     as3p, ad3p);
    xcvt_kernel<<<(N * F_IN / 8 + 255) / 256, 256, 0, stream>>>(x, x16, N * F_IN / 8);

    int ny = (N + BM - 1) / BM;
    int sgrid = (N * 4 + 255) / 256;
    int wgrid = (N + 3) / 4;

    // ---- layer 1: one GEMM, N=512 (cols 0-255 -> xh f16, 256-511 -> lin1h f16 + l1b) ----
    gemm_f16<<<4 * ny, 256, 0, stream>>>(x16, C1, N, F_IN, 512, 4, ny,
                                         256, xh, 256, 0, lin1h, l1b, 256);
    alpha_wave_256<<<wgrid, 256, 0, stream>>>(xh, a1s, a1d, as_, ad_, N);
    stats_alpha_kernel<<<sgrid, 256, 0, stream>>>(rowp, col, as_, ad_, alphaE, N);
    agg_wave_256<<<wgrid, 256, 0, stream>>>(xh, rowp, col, alphaE, b1, lin1h, h1f, N);

    // ---- layer 2: N=256, residual = h1f ----
    gemm_f16<<<2 * ny, 256, 0, stream>>>(h1f, C2, N, HC12, 256, 2, ny,
                                         256, xh, 256, 0, nullptr, nullptr, 0);
    alpha_wave_256<<<wgrid, 256, 0, stream>>>(xh, a2s, a2d, as_, ad_, N);
    stats_alpha_kernel<<<sgrid, 256, 0, stream>>>(rowp, col, as_, ad_, alphaE, N);
    agg_wave_256<<<wgrid, 256, 0, stream>>>(xh, rowp, col, alphaE, b2, h1f, h2f, N);

    // ---- layer 3: one GEMM, N=605, padded xh3 (stride 512), cols 484-604 -> lin3h f16 + l3b ----
    gemm_f16<<<5 * ny, 256, 0, stream>>>(h2f, C3, N, HC12, 605, 5, ny,
                                         484, xh, HC3P, 1, lin3h, l3b, L3STR);
    alpha3_wave<<<wgrid, 256, 0, stream>>>(xh, as3p, ad3p, as_, ad_, N);
    stats_alpha_kernel<<<sgrid, 256, 0, stream>>>(rowp, col, as_, ad_, alphaE, N);
    agg_wave_out<<<wgrid, 256, 0, stream>>>(xh, rowp, col, alphaE, b3, lin3h, (float*)d_out, N);
}

// Round 6
// 500.022 us; speedup vs baseline: 1.1736x; 1.0148x over previous
//
#include <hip/hip_runtime.h>
#include <cstdint>
#include <cstddef>

#define F_IN 128
#define HC12 256   // HEADS*HID for layers 1/2
#define HC3P 512   // padded row stride (u16) for layer-3 activations: 4 heads x 128
#define NCLS 121
#define L3STR 128  // lin3h row stride (u16)

typedef unsigned short u16;
typedef unsigned int u32;
typedef __attribute__((ext_vector_type(8))) short short8;
typedef __attribute__((ext_vector_type(8))) __fp16 half8;
typedef __attribute__((ext_vector_type(4))) float float4v;

static __device__ __forceinline__ float lrelu(float x) { return x > 0.f ? x : 0.2f * x; }

static __device__ __forceinline__ u16 f2h(float f) {
    union { __fp16 h; u16 u; } v; v.h = (__fp16)f; return v.u;
}
static __device__ __forceinline__ float h2f(u16 u) {
    union { u16 u; __fp16 h; } v; v.u = u; return (float)v.h;
}

static __device__ __forceinline__ void gload16(const u16* g, u16* l) {
    __builtin_amdgcn_global_load_lds((const __attribute__((address_space(1))) void*)g,
                                     (__attribute__((address_space(3))) void*)l,
                                     16, 0, 0);
}

// ---------------- CSR build ----------------
__global__ void hist_kernel(const int* __restrict__ dst, int* __restrict__ deg, int E) {
    int e = blockIdx.x * 256 + threadIdx.x;
    if (e < E) atomicAdd(&deg[dst[e]], 1);
}

__global__ __launch_bounds__(1024) void scan_kernel(const int* __restrict__ deg,
                                                    int* __restrict__ rowp, int N) {
    __shared__ int swave[16];
    __shared__ int s_carry;
    int tid = threadIdx.x;
    int w = tid >> 6, lane = tid & 63;
    if (tid == 0) { rowp[0] = 0; s_carry = 0; }
    __syncthreads();
    for (int base = 0; base < N; base += 4096) {
        int i0 = base + tid * 4;
        int v0 = (i0     < N) ? deg[i0]     : 0;
        int v1 = (i0 + 1 < N) ? deg[i0 + 1] : 0;
        int v2 = (i0 + 2 < N) ? deg[i0 + 2] : 0;
        int v3 = (i0 + 3 < N) ? deg[i0 + 3] : 0;
        int t = v0 + v1 + v2 + v3;
        int sc = t;
#pragma unroll
        for (int off = 1; off < 64; off <<= 1) {
            int u = __shfl_up(sc, off, 64);
            if (lane >= off) sc += u;
        }
        if (lane == 63) swave[w] = sc;
        __syncthreads();
        if (w == 0) {
            int ws = (lane < 16) ? swave[lane] : 0;
#pragma unroll
            for (int off = 1; off < 16; off <<= 1) {
                int u = __shfl_up(ws, off, 64);
                if (lane >= off) ws += u;
            }
            if (lane < 16) swave[lane] = ws;
        }
        __syncthreads();
        int carry = s_carry;
        int tb = carry + ((w > 0) ? swave[w - 1] : 0) + sc - t;
        if (i0     < N) rowp[i0 + 1] = tb + v0;
        if (i0 + 1 < N) rowp[i0 + 2] = tb + v0 + v1;
        if (i0 + 2 < N) rowp[i0 + 3] = tb + v0 + v1 + v2;
        if (i0 + 3 < N) rowp[i0 + 4] = tb + t;
        __syncthreads();
        if (tid == 1023) s_carry = carry + swave[15];
        __syncthreads();
    }
}

__global__ void scatter_kernel(const int* __restrict__ src, const int* __restrict__ dst,
                               const int* __restrict__ rowp, int* __restrict__ cur,
                               int* __restrict__ col, int E) {
    int e = blockIdx.x * 256 + threadIdx.x;
    if (e < E) {
        int d = dst[e];
        int pos = rowp[d] + atomicAdd(&cur[d], 1);
        col[pos] = src[e];
    }
}

// ---------------- fused weight transpose to f16 (+ padded a3 tables) ----------------
__global__ void cvtT_all_kernel(const float* W1, const float* l1W, const float* W2,
                                const float* W3, const float* l3W,
                                const float* a3s, const float* a3d,
                                u16* C1, u16* C2, u16* C3,
                                float* as3p, float* ad3p) {
    int i = blockIdx.x * 256 + threadIdx.x;
    if (i >= 285952) {
        int j = i - 285952;
        if (j < 1024) {
            int t = j >> 9, k = j & 511;
            int h = k >> 7, c = k & 127;
            const float* a = t ? a3d : a3s;
            float v = (c < NCLS) ? a[h * NCLS + c] : 0.f;
            (t ? ad3p : as3p)[k] = v;
        }
        return;
    }
    const float* B; u16* o; int K, N;
    if (i < 32768)       { B = W1;  o = C1;             K = 128; N = 256; }
    else if (i < 65536)  { B = l1W; o = C1 + 256 * 128; K = 128; N = 256; i -= 32768; }
    else if (i < 131072) { B = W2;  o = C2;             K = 256; N = 256; i -= 65536; }
    else if (i < 254976) { B = W3;  o = C3;             K = 256; N = 484; i -= 131072; }
    else                 { B = l3W; o = C3 + 484 * 256; K = 256; N = 121; i -= 254976; }
    int n = i % N, k = i / N;
    o[(size_t)n * K + k] = f2h(B[(size_t)k * N + n]);
}

// ---------------- x fp32 -> f16 ----------------
__global__ __launch_bounds__(256) void xcvt_kernel(const float* __restrict__ x,
                                                   u16* __restrict__ o, int total8) {
    int i = blockIdx.x * 256 + threadIdx.x;
    if (i >= total8) return;
    const float4* p = (const float4*)(x + (size_t)i * 8);
    float4 a = p[0], b = p[1];
    union { u16 u[8]; short8 v; } r;
    r.u[0] = f2h(a.x); r.u[1] = f2h(a.y); r.u[2] = f2h(a.z); r.u[3] = f2h(a.w);
    r.u[4] = f2h(b.x); r.u[5] = f2h(b.y); r.u[6] = f2h(b.z); r.u[7] = f2h(b.w);
    *(short8*)(o + (size_t)i * 8) = r.v;
}

// ---------------- f16 MFMA GEMM, 128x128 tile, global_load_lds staging ----------------
#define BM 128
#define BN 128
#define BK 32

__global__ __launch_bounds__(256, 3) void gemm_f16(const u16* __restrict__ A16,
                                                   const u16* __restrict__ BT,
                                                   int M, int K, int Ntot,
                                                   int nx, int ny,
                                                   int Nb, u16* __restrict__ Cb, int strideB,
                                                   int pad121,
                                                   u16* __restrict__ Cf16,
                                                   const float* __restrict__ biasf, int strideF) {
    __shared__ __align__(16) u16 sA[BM * BK];
    __shared__ __align__(16) u16 sB[BN * BK];
    int tid = threadIdx.x;
    int wave = tid >> 6, lane = tid & 63;
    int wr = wave >> 1, wc = wave & 1;

    // XCD-aware block swizzle
    int bid = blockIdx.x;
    int G = nx * 8;
    int g = bid / G;
    int rem = ny - g * 8;
    int rb, cb;
    if (rem >= 8) {
        int r = bid - g * G;
        rb = g * 8 + (r & 7);
        cb = r >> 3;
    } else {
        int t = bid - g * G;
        rb = g * 8 + t % rem;
        cb = t / rem;
    }
    int m0 = rb * BM, n0 = cb * BN;

    int fm = lane & 15;
    int q = lane >> 4;

    int srow = lane >> 2;
    int sch = (lane & 3) * 8;
    u16* lA0 = &sA[(wave * 32) * BK];
    u16* lA1 = &sA[(wave * 32 + 16) * BK];
    u16* lB0 = &sB[(wave * 32) * BK];
    u16* lB1 = &sB[(wave * 32 + 16) * BK];
    int ar0 = min(m0 + wave * 32 + srow, M - 1);
    int ar1 = min(m0 + wave * 32 + 16 + srow, M - 1);
    int br0 = min(n0 + wave * 32 + srow, Ntot - 1);
    int br1 = min(n0 + wave * 32 + 16 + srow, Ntot - 1);

    float4v acc[4][4];
#pragma unroll
    for (int i = 0; i < 4; i++)
#pragma unroll
        for (int j = 0; j < 4; j++) acc[i][j] = (float4v){0.f, 0.f, 0.f, 0.f};

    for (int kc = 0; kc < K; kc += BK) {
        gload16(&A16[(size_t)ar0 * K + kc + sch], lA0);
        gload16(&A16[(size_t)ar1 * K + kc + sch], lA1);
        gload16(&BT[(size_t)br0 * K + kc + sch], lB0);
        gload16(&BT[(size_t)br1 * K + kc + sch], lB1);
        __syncthreads();

        half8 ah[4];
#pragma unroll
        for (int mi = 0; mi < 4; mi++)
            ah[mi] = *(const half8*)&sA[(wr * 64 + mi * 16 + fm) * BK + q * 8];
#pragma unroll
        for (int ni = 0; ni < 4; ni++) {
            half8 bh = *(const half8*)&sB[(wc * 64 + ni * 16 + fm) * BK + q * 8];
#pragma unroll
            for (int mi = 0; mi < 4; mi++)
                acc[mi][ni] = __builtin_amdgcn_mfma_f32_16x16x32_f16(ah[mi], bh, acc[mi][ni], 0, 0, 0);
        }
        __syncthreads();
    }

#pragma unroll
    for (int mi = 0; mi < 4; mi++) {
#pragma unroll
        for (int ni = 0; ni < 4; ni++) {
            int colg = n0 + wc * 64 + ni * 16 + fm;
            if (colg >= Ntot) continue;
            int cg = colg;
            if (pad121 && colg < Nb) {
                int hh = (colg * 1084) >> 17;   // colg/121 for colg<484
                cg = colg + 7 * hh;             // head*128 + class
            }
#pragma unroll
            for (int r = 0; r < 4; r++) {
                int rowg = m0 + wr * 64 + mi * 16 + q * 4 + r;
                if (rowg >= M) continue;
                float v = acc[mi][ni][r];
                if (colg < Nb) {
                    Cb[(size_t)rowg * strideB + cg] = f2h(v);
                } else {
                    int cf = colg - Nb;
                    Cf16[(size_t)rowg * strideF + cf] = f2h(v + biasf[cf]);
                }
            }
        }
    }
}

// ---------------- wave-per-node attention coefficients, C=64 (layers 1/2) ----------------
__global__ __launch_bounds__(256) void alpha_wave_256(const u16* __restrict__ xh,
                                                      const float* __restrict__ a_s,
                                                      const float* __restrict__ a_d,
                                                      float* __restrict__ as_o,
                                                      float* __restrict__ ad_o, int N) {
    int lane = threadIdx.x & 63;
    int n = blockIdx.x * 4 + (threadIdx.x >> 6);
    if (n >= N) return;
    int c = lane * 4;
    uint2 v = *(const uint2*)&xh[(size_t)n * HC12 + c];
    float4 s4 = *(const float4*)&a_s[c];
    float4 d4 = *(const float4*)&a_d[c];
    float x0 = h2f((u16)(v.x & 0xffff)), x1 = h2f((u16)(v.x >> 16));
    float x2 = h2f((u16)(v.y & 0xffff)), x3 = h2f((u16)(v.y >> 16));
    float ss = x0 * s4.x + x1 * s4.y + x2 * s4.z + x3 * s4.w;
    float sd = x0 * d4.x + x1 * d4.y + x2 * d4.z + x3 * d4.w;
#pragma unroll
    for (int o = 1; o < 16; o <<= 1) {
        ss += __shfl_xor(ss, o, 64);
        sd += __shfl_xor(sd, o, 64);
    }
    if ((lane & 15) == 0) {
        as_o[n * 4 + (lane >> 4)] = ss;
        ad_o[n * 4 + (lane >> 4)] = sd;
    }
}

// ---------------- wave-per-node layer-3 attention coefficients (padded, vectorized) ----------------
__global__ __launch_bounds__(256) void alpha3_wave(const u16* __restrict__ xh3,
                                                   const float* __restrict__ as3p,
                                                   const float* __restrict__ ad3p,
                                                   float* __restrict__ as_o,
                                                   float* __restrict__ ad_o, int N) {
    int l = threadIdx.x & 63;
    int n = blockIdx.x * 4 + (threadIdx.x >> 6);
    if (n >= N) return;
    int h = l >> 4, li = l & 15;
    int c0 = li * 8;
    uint4 v = *(const uint4*)&xh3[(size_t)n * HC3P + l * 8];
    float4 s0 = *(const float4*)&as3p[l * 8];
    float4 s1 = *(const float4*)&as3p[l * 8 + 4];
    float4 d0 = *(const float4*)&ad3p[l * 8];
    float4 d1 = *(const float4*)&ad3p[l * 8 + 4];
    u32 ww[4] = {v.x, v.y, v.z, v.w};
    float xs[8];
#pragma unroll
    for (int j = 0; j < 8; j++) {
        float xf = h2f((u16)((ww[j >> 1] >> ((j & 1) * 16)) & 0xffff));
        xs[j] = (c0 + j < NCLS) ? xf : 0.f;   // mask pad garbage (could be NaN)
    }
    float ss = xs[0] * s0.x + xs[1] * s0.y + xs[2] * s0.z + xs[3] * s0.w
             + xs[4] * s1.x + xs[5] * s1.y + xs[6] * s1.z + xs[7] * s1.w;
    float sd = xs[0] * d0.x + xs[1] * d0.y + xs[2] * d0.z + xs[3] * d0.w
             + xs[4] * d1.x + xs[5] * d1.y + xs[6] * d1.z + xs[7] * d1.w;
#pragma unroll
    for (int o = 1; o < 16; o <<= 1) {
        ss += __shfl_xor(ss, o, 64);
        sd += __shfl_xor(sd, o, 64);
    }
    if (li == 0) {
        as_o[n * 4 + h] = ss;
        ad_o[n * 4 + h] = sd;
    }
}

// ---------------- wave-per-node softmax stats + per-edge alpha ----------------
// lane = (edge-slot el = l>>2, head h = l&3). 16-edge chunks; per-head reduce via
// shfl_xor offsets 4..32 (preserves h). Fast path deg<=16 keeps logits in regs.
__global__ __launch_bounds__(256) void stats_wave(const int* __restrict__ rowp,
                                                  const int* __restrict__ col,
                                                  const float* __restrict__ asrc,
                                                  const float* __restrict__ adst,
                                                  float* __restrict__ alphaE, int N) {
    int l = threadIdx.x & 63;
    int n = blockIdx.x * 4 + (threadIdx.x >> 6);
    if (n >= N) return;
    int r0 = rowp[n], r1 = rowp[n + 1];
    if (r0 == r1) return;
    int h = l & 3, el = l >> 2;
    float ad = adst[n * 4 + h];
    if (r1 - r0 <= 16) {
        int e = r0 + el;
        bool v = e < r1;
        int sc = col[v ? e : r0];
        float lg = lrelu(asrc[sc * 4 + h] + ad);
        float m = v ? lg : -3.4e38f;
#pragma unroll
        for (int o = 4; o < 64; o <<= 1) m = fmaxf(m, __shfl_xor(m, o, 64));
        float ex = v ? __expf(lg - m) : 0.f;
        float s = ex;
#pragma unroll
        for (int o = 4; o < 64; o <<= 1) s += __shfl_xor(s, o, 64);
        if (v) alphaE[(size_t)e * 4 + h] = ex / (s + 1e-16f);
    } else {
        float m = -3.4e38f, s = 0.f;
        for (int kb = r0; kb < r1; kb += 16) {
            int e = kb + el;
            bool v = e < r1;
            int sc = col[v ? e : r0];
            float lg = lrelu(asrc[sc * 4 + h] + ad);
            float cm = v ? lg : -3.4e38f;
#pragma unroll
            for (int o = 4; o < 64; o <<= 1) cm = fmaxf(cm, __shfl_xor(cm, o, 64));
            float nm = fmaxf(m, cm);
            float ex = v ? __expf(lg - nm) : 0.f;
            float cs = ex;
#pragma unroll
            for (int o = 4; o < 64; o <<= 1) cs += __shfl_xor(cs, o, 64);
            s = s * __expf(m - nm) + cs;
            m = nm;
        }
        float rd = 1.f / (s + 1e-16f);
        for (int kb = r0; kb < r1; kb += 16) {
            int e = kb + el;
            if (e < r1) {
                int sc = col[e];
                float lg = lrelu(asrc[sc * 4 + h] + ad);
                alphaE[(size_t)e * 4 + h] = __expf(lg - m) * rd;
            }
        }
    }
}

// ---------------- wave-per-node aggregate, HC=256, 2 edges/iteration ----------------
__global__ __launch_bounds__(256) void agg_wave_256(const u16* __restrict__ xh,
                                                    const int* __restrict__ rowp,
                                                    const int* __restrict__ col,
                                                    const float* __restrict__ alphaE,
                                                    const float* __restrict__ bias,
                                                    const u16* __restrict__ res16,
                                                    u16* __restrict__ out16, int N) {
    int l = threadIdx.x & 63;
    int n = blockIdx.x * 4 + (threadIdx.x >> 6);
    if (n >= N) return;
    int r0 = rowp[n], r1 = rowp[n + 1];
    int s = l >> 5, li = l & 31;
    int c = li * 8;
    int h = li >> 3;
    float acc[8] = {0.f, 0.f, 0.f, 0.f, 0.f, 0.f, 0.f, 0.f};
    for (int kb = r0; kb < r1; kb += 16) {
        int cn = min(16, r1 - kb);
        int cidx = col[kb + (l & 15)];
        float alv = alphaE[(size_t)kb * 4 + l];
        int npair = (cn + 1) >> 1;
#pragma unroll 4
        for (int k = 0; k < npair; k++) {
            int e = 2 * k + s;
            int em = e < cn ? e : cn - 1;
            int src = __shfl(cidx, em, 64);
            float al = __shfl(alv, em * 4 + h, 64);
            if (e >= cn) al = 0.f;
            uint4 v = *(const uint4*)&xh[(size_t)src * HC12 + c];
            acc[0] += al * h2f((u16)(v.x & 0xffff));
            acc[1] += al * h2f((u16)(v.x >> 16));
            acc[2] += al * h2f((u16)(v.y & 0xffff));
            acc[3] += al * h2f((u16)(v.y >> 16));
            acc[4] += al * h2f((u16)(v.z & 0xffff));
            acc[5] += al * h2f((u16)(v.z >> 16));
            acc[6] += al * h2f((u16)(v.w & 0xffff));
            acc[7] += al * h2f((u16)(v.w >> 16));
        }
    }
#pragma unroll
    for (int j = 0; j < 8; j++) acc[j] += __shfl_xor(acc[j], 32, 64);
    if (l < 32) {
        uint4 rv = *(const uint4*)&res16[(size_t)n * HC12 + c];
        u32 rw[4] = {rv.x, rv.y, rv.z, rv.w};
        float4 b0 = *(const float4*)&bias[c];
        float4 b1v = *(const float4*)&bias[c + 4];
        float bb[8] = {b0.x, b0.y, b0.z, b0.w, b1v.x, b1v.y, b1v.z, b1v.w};
        union { u16 u[8]; uint4 v; } p;
#pragma unroll
        for (int j = 0; j < 8; j++) {
            float rf = h2f((u16)((rw[j >> 1] >> ((j & 1) * 16)) & 0xffff));
            float vv = acc[j] + bb[j] + rf;
            float ev = vv > 0.f ? vv : expm1f(vv);
            p.u[j] = f2h(ev);
        }
        *(uint4*)&out16[(size_t)n * HC12 + c] = p.v;
    }
}

// ---------------- layer-3 aggregate: 2 nodes per wave (32 lanes x 16 ch), no LDS ----------------
// lane li (0..31) owns u16 channels li*16..+15 of the 512-u16 padded row: head = li>>3,
// class block = (li&7)*16. Head-mean via shfl_xor(8,16) within the half-wave.
__global__ __launch_bounds__(256) void agg_wave_out(const u16* __restrict__ xh3,
                                                    const int* __restrict__ rowp,
                                                    const int* __restrict__ col,
                                                    const float* __restrict__ alphaE,
                                                    const float* __restrict__ b3,
                                                    const u16* __restrict__ lin3h,
                                                    float* __restrict__ out, int N) {
    int l = threadIdx.x & 63;
    int half = l >> 5, li = l & 31;
    int bl = l & 32;
    int n = blockIdx.x * 8 + (threadIdx.x >> 6) * 2 + half;
    bool nv = n < N;
    int r0 = nv ? rowp[n] : 0;
    int r1 = nv ? rowp[n + 1] : 0;
    float acc[16];
#pragma unroll
    for (int j = 0; j < 16; j++) acc[j] = 0.f;
    // 8-edge chunks; halves may diverge in trip count (shfl only within own half -> safe)
    for (int kb = r0; kb < r1; kb += 8) {
        int ec = min(8, r1 - kb);
        int ce = kb + (li & 7);
        int cidx = col[ce < r1 ? ce : r0];
        float alv = alphaE[(size_t)kb * 4 + li];   // 8 edges x 4 heads
        for (int k = 0; k < ec; k++) {
            int src = __shfl(cidx, bl + k, 64);
            float al = __shfl(alv, bl + k * 4 + (li >> 3), 64);
            const u16* row = xh3 + (size_t)src * HC3P + li * 16;
            uint4 v0 = *(const uint4*)&row[0];
            uint4 v1 = *(const uint4*)&row[8];
            u32 w0[4] = {v0.x, v0.y, v0.z, v0.w};
            u32 w1[4] = {v1.x, v1.y, v1.z, v1.w};
#pragma unroll
            for (int jj = 0; jj < 4; jj++) {
                acc[2 * jj]     += al * h2f((u16)(w0[jj] & 0xffff));
                acc[2 * jj + 1] += al * h2f((u16)(w0[jj] >> 16));
                acc[8 + 2 * jj]     += al * h2f((u16)(w1[jj] & 0xffff));
                acc[8 + 2 * jj + 1] += al * h2f((u16)(w1[jj] >> 16));
            }
        }
    }
    // head-mean: xor 8 flips head bit0, xor 16 flips head bit1 (class block li&7 preserved)
#pragma unroll
    for (int j = 0; j < 16; j++) {
        acc[j] += __shfl_xor(acc[j], 8, 64);
        acc[j] += __shfl_xor(acc[j], 16, 64);
    }
    if (nv && li < 8) {
        int c0 = li * 16;
        uint4 l0 = *(const uint4*)&lin3h[(size_t)n * L3STR + c0];
        uint4 l1 = *(const uint4*)&lin3h[(size_t)n * L3STR + c0 + 8];
        u32 lw[8] = {l0.x, l0.y, l0.z, l0.w, l1.x, l1.y, l1.z, l1.w};
#pragma unroll
        for (int j = 0; j < 16; j++) {
            int cc = c0 + j;
            if (cc < NCLS) {
                float lf = h2f((u16)((lw[j >> 1] >> ((j & 1) * 16)) & 0xffff));
                out[(size_t)n * NCLS + cc] = 0.25f * acc[j] + b3[cc] + lf;
            }
        }
    }
}

extern "C" void kernel_launch(void* const* d_in, const int* in_sizes, int n_in,
                              void* d_out, int out_size, void* d_ws, size_t ws_size,
                              hipStream_t stream) {
    const float* x   = (const float*)d_in[0];
    const int*   ei  = (const int*)d_in[1];
    const float* W1  = (const float*)d_in[2];
    const float* a1s = (const float*)d_in[3];
    const float* a1d = (const float*)d_in[4];
    const float* b1  = (const float*)d_in[5];
    const float* l1W = (const float*)d_in[6];
    const float* l1b = (const float*)d_in[7];
    const float* W2  = (const float*)d_in[8];
    const float* a2s = (const float*)d_in[9];
    const float* a2d = (const float*)d_in[10];
    const float* b2  = (const float*)d_in[11];
    const float* W3  = (const float*)d_in[12];
    const float* a3s = (const float*)d_in[13];
    const float* a3d = (const float*)d_in[14];
    const float* b3  = (const float*)d_in[15];
    const float* l3W = (const float*)d_in[16];
    const float* l3b = (const float*)d_in[17];

    const int N = in_sizes[0] / F_IN;   // 50000
    const int E = in_sizes[1] / 2;      // 400000
    const int* srcv = ei;
    const int* dstv = ei + E;

    char* ws = (char*)d_ws;
    size_t off = 0;
    auto alloc = [&](size_t bytes) -> char* {
        char* p = ws + off;
        off += (bytes + 255) & ~(size_t)255;
        return p;
    };
    u16*   xh    = (u16*)alloc((size_t)N * HC3P * 2 + 256);
    u16*   x16   = (u16*)alloc((size_t)N * F_IN * 2);
    u16*   h1f   = (u16*)alloc((size_t)N * HC12 * 2);
    u16*   h2f   = (u16*)alloc((size_t)N * HC12 * 2);
    u16*   lin1h = (u16*)alloc((size_t)N * HC12 * 2);
    u16*   lin3h = (u16*)alloc((size_t)N * L3STR * 2);
    float* as_   = (float*)alloc((size_t)N * 4 * 4);
    float* ad_   = (float*)alloc((size_t)N * 4 * 4);
    int* rowp    = (int*)alloc((size_t)(N + 1) * 4);
    int* degc    = (int*)alloc((size_t)N * 4);
    int* cur     = (int*)alloc((size_t)N * 4);
    int* col     = (int*)alloc((size_t)E * 4 + 256);
    float* alphaE = (float*)alloc((size_t)E * 4 * 4 + 256);
    u16* C1 = (u16*)alloc((size_t)512 * 128 * 2);
    u16* C2 = (u16*)alloc((size_t)256 * 256 * 2);
    u16* C3 = (u16*)alloc((size_t)605 * 256 * 2);
    float* as3p = (float*)alloc(512 * 4);
    float* ad3p = (float*)alloc(512 * 4);
    (void)ws_size; (void)n_in; (void)out_size;

    // ---- CSR build ----
    hipMemsetAsync(degc, 0, (size_t)N * 4, stream);
    hipMemsetAsync(cur, 0, (size_t)N * 4, stream);
    hist_kernel<<<(E + 255) / 256, 256, 0, stream>>>(dstv, degc, E);
    scan_kernel<<<1, 1024, 0, stream>>>(degc, rowp, N);
    scatter_kernel<<<(E + 255) / 256, 256, 0, stream>>>(srcv, dstv, rowp, cur, col, E);

    // ---- weight transpose + x conversion + padded a3 tables ----
    cvtT_all_kernel<<<(285952 + 1024 + 255) / 256, 256, 0, stream>>>(W1, l1W, W2, W3, l3W,
                                                                     a3s, a3d, C1, C2, C3,
                                                                     as3p, ad3p);
    xcvt_kernel<<<(N * F_IN / 8 + 255) / 256, 256, 0, stream>>>(x, x16, N * F_IN / 8);

    int ny = (N + BM - 1) / BM;
    int wgrid = (N + 3) / 4;
    int wgrid8 = (N + 7) / 8;

    // ---- layer 1: one GEMM, N=512 (cols 0-255 -> xh f16, 256-511 -> lin1h f16 + l1b) ----
    gemm_f16<<<4 * ny, 256, 0, stream>>>(x16, C1, N, F_IN, 512, 4, ny,
                                         256, xh, 256, 0, lin1h, l1b, 256);
    alpha_wave_256<<<wgrid, 256, 0, stream>>>(xh, a1s, a1d, as_, ad_, N);
    stats_wave<<<wgrid, 256, 0, stream>>>(rowp, col, as_, ad_, alphaE, N);
    agg_wave_256<<<wgrid, 256, 0, stream>>>(xh, rowp, col, alphaE, b1, lin1h, h1f, N);

    // ---- layer 2: N=256, residual = h1f ----
    gemm_f16<<<2 * ny, 256, 0, stream>>>(h1f, C2, N, HC12, 256, 2, ny,
                                         256, xh, 256, 0, nullptr, nullptr, 0);
    alpha_wave_256<<<wgrid, 256, 0, stream>>>(xh, a2s, a2d, as_, ad_, N);
    stats_wave<<<wgrid, 256, 0, stream>>>(rowp, col, as_, ad_, alphaE, N);
    agg_wave_256<<<wgrid, 256, 0, stream>>>(xh, rowp, col, alphaE, b2, h1f, h2f, N);

    // ---- layer 3: one GEMM, N=605, padded xh3 (stride 512), cols 484-604 -> lin3h f16 + l3b ----
    gemm_f16<<<5 * ny, 256, 0, stream>>>(h2f, C3, N, HC12, 605, 5, ny,
                                         484, xh, HC3P, 1, lin3h, l3b, L3STR);
    alpha3_wave<<<wgrid, 256, 0, stream>>>(xh, as3p, ad3p, as_, ad_, N);
    stats_wave<<<wgrid, 256, 0, stream>>>(rowp, col, as_, ad_, alphaE, N);
    agg_wave_out<<<wgrid8, 256, 0, stream>>>(xh, rowp, col, alphaE, b3, lin3h, (float*)d_out, N);
}

// Round 7
// 448.958 us; speedup vs baseline: 1.3070x; 1.1137x over previous
//
#include <hip/hip_runtime.h>
#include <cstdint>
#include <cstddef>

#define F_IN 128
#define HC12 256   // HEADS*HID for layers 1/2
#define HC3P 512   // padded row stride (u16) for layer-3 activations: 4 heads x 128
#define NCLS 121
#define L3STR 128  // lin3h row stride (u16)

typedef unsigned short u16;
typedef unsigned int u32;
typedef __attribute__((ext_vector_type(8))) short short8;
typedef __attribute__((ext_vector_type(8))) __fp16 half8;
typedef __attribute__((ext_vector_type(4))) float float4v;

static __device__ __forceinline__ float lrelu(float x) { return x > 0.f ? x : 0.2f * x; }

static __device__ __forceinline__ u16 f2h(float f) {
    union { __fp16 h; u16 u; } v; v.h = (__fp16)f; return v.u;
}
static __device__ __forceinline__ float h2f(u16 u) {
    union { u16 u; __fp16 h; } v; v.u = u; return (float)v.h;
}

static __device__ __forceinline__ void gload16(const u16* g, u16* l) {
    __builtin_amdgcn_global_load_lds((const __attribute__((address_space(1))) void*)g,
                                     (__attribute__((address_space(3))) void*)l,
                                     16, 0, 0);
}

// ---------------- CSR build ----------------
__global__ void hist_kernel(const int* __restrict__ dst, int* __restrict__ deg, int E) {
    int e = blockIdx.x * 256 + threadIdx.x;
    if (e < E) atomicAdd(&deg[dst[e]], 1);
}

// ---- parallel 3-phase scan (replaces single-block scan) ----
__global__ __launch_bounds__(256) void scan_part(const int* __restrict__ deg,
                                                 int* __restrict__ part, int N) {
    int b = blockIdx.x;
    int i0 = b * 1024 + threadIdx.x * 4;
    int t = 0;
    if (i0     < N) t += deg[i0];
    if (i0 + 1 < N) t += deg[i0 + 1];
    if (i0 + 2 < N) t += deg[i0 + 2];
    if (i0 + 3 < N) t += deg[i0 + 3];
#pragma unroll
    for (int o = 1; o < 64; o <<= 1) t += __shfl_xor(t, o, 64);
    __shared__ int sw[4];
    int w = threadIdx.x >> 6, lane = threadIdx.x & 63;
    if (!lane) sw[w] = t;
    __syncthreads();
    if (threadIdx.x == 0) part[b] = sw[0] + sw[1] + sw[2] + sw[3];
}

__global__ void scan_mid(int* __restrict__ part, int nb) {
    int lane = threadIdx.x;   // 64 threads
    __shared__ int carry_s;
    if (lane == 0) carry_s = 0;
    __syncthreads();
    for (int base = 0; base < nb; base += 64) {
        int i = base + lane;
        int v = (i < nb) ? part[i] : 0;
        int sc = v;
#pragma unroll
        for (int o = 1; o < 64; o <<= 1) {
            int u = __shfl_up(sc, o, 64);
            if (lane >= o) sc += u;
        }
        int carry = carry_s;
        if (i < nb) part[i] = carry + sc - v;   // exclusive prefix
        __syncthreads();
        if (lane == 63) carry_s = carry + sc;
        __syncthreads();
    }
}

__global__ __launch_bounds__(256) void scan_final(const int* __restrict__ deg,
                                                  const int* __restrict__ part,
                                                  int* __restrict__ rowp, int N) {
    int b = blockIdx.x;
    int tid = threadIdx.x;
    int w = tid >> 6, lane = tid & 63;
    int i0 = b * 1024 + tid * 4;
    int v0 = (i0     < N) ? deg[i0]     : 0;
    int v1 = (i0 + 1 < N) ? deg[i0 + 1] : 0;
    int v2 = (i0 + 2 < N) ? deg[i0 + 2] : 0;
    int v3 = (i0 + 3 < N) ? deg[i0 + 3] : 0;
    int t = v0 + v1 + v2 + v3;
    int sc = t;
#pragma unroll
    for (int o = 1; o < 64; o <<= 1) {
        int u = __shfl_up(sc, o, 64);
        if (lane >= o) sc += u;
    }
    __shared__ int sw2[4];
    if (lane == 63) sw2[w] = sc;
    __syncthreads();
    int cw = 0;
    for (int x = 0; x < w; x++) cw += sw2[x];
    int tb = part[b] + cw + sc - t;
    if (i0     < N) rowp[i0 + 1] = tb + v0;
    if (i0 + 1 < N) rowp[i0 + 2] = tb + v0 + v1;
    if (i0 + 2 < N) rowp[i0 + 3] = tb + v0 + v1 + v2;
    if (i0 + 3 < N) rowp[i0 + 4] = tb + t;
    if (b == 0 && tid == 0) rowp[0] = 0;
}

__global__ void scatter_kernel(const int* __restrict__ src, const int* __restrict__ dst,
                               const int* __restrict__ rowp, int* __restrict__ cur,
                               int* __restrict__ col, int E) {
    int e = blockIdx.x * 256 + threadIdx.x;
    if (e < E) {
        int d = dst[e];
        int pos = rowp[d] + atomicAdd(&cur[d], 1);
        col[pos] = src[e];
    }
}

// ---------------- fused weight transpose to f16 (+ padded a3 tables) ----------------
__global__ void cvtT_all_kernel(const float* W1, const float* l1W, const float* W2,
                                const float* W3, const float* l3W,
                                const float* a3s, const float* a3d,
                                u16* C1, u16* C2, u16* C3,
                                float* as3p, float* ad3p) {
    int i = blockIdx.x * 256 + threadIdx.x;
    if (i >= 285952) {
        int j = i - 285952;
        if (j < 1024) {
            int t = j >> 9, k = j & 511;
            int h = k >> 7, c = k & 127;
            const float* a = t ? a3d : a3s;
            float v = (c < NCLS) ? a[h * NCLS + c] : 0.f;
            (t ? ad3p : as3p)[k] = v;
        }
        return;
    }
    const float* B; u16* o; int K, N;
    if (i < 32768)       { B = W1;  o = C1;             K = 128; N = 256; }
    else if (i < 65536)  { B = l1W; o = C1 + 256 * 128; K = 128; N = 256; i -= 32768; }
    else if (i < 131072) { B = W2;  o = C2;             K = 256; N = 256; i -= 65536; }
    else if (i < 254976) { B = W3;  o = C3;             K = 256; N = 484; i -= 131072; }
    else                 { B = l3W; o = C3 + 484 * 256; K = 256; N = 121; i -= 254976; }
    int n = i % N, k = i / N;
    o[(size_t)n * K + k] = f2h(B[(size_t)k * N + n]);
}

// ---------------- x fp32 -> f16 ----------------
__global__ __launch_bounds__(256) void xcvt_kernel(const float* __restrict__ x,
                                                   u16* __restrict__ o, int total8) {
    int i = blockIdx.x * 256 + threadIdx.x;
    if (i >= total8) return;
    const float4* p = (const float4*)(x + (size_t)i * 8);
    float4 a = p[0], b = p[1];
    union { u16 u[8]; short8 v; } r;
    r.u[0] = f2h(a.x); r.u[1] = f2h(a.y); r.u[2] = f2h(a.z); r.u[3] = f2h(a.w);
    r.u[4] = f2h(b.x); r.u[5] = f2h(b.y); r.u[6] = f2h(b.z); r.u[7] = f2h(b.w);
    *(short8*)(o + (size_t)i * 8) = r.v;
}

// ---------------- f16 MFMA GEMM, 128x128 tile, global_load_lds staging ----------------
#define BM 128
#define BN 128
#define BK 32

__global__ __launch_bounds__(256, 3) void gemm_f16(const u16* __restrict__ A16,
                                                   const u16* __restrict__ BT,
                                                   int M, int K, int Ntot,
                                                   int nx, int ny,
                                                   int Nb, u16* __restrict__ Cb, int strideB,
                                                   int pad121,
                                                   u16* __restrict__ Cf16,
                                                   const float* __restrict__ biasf, int strideF) {
    __shared__ __align__(16) u16 sA[BM * BK];
    __shared__ __align__(16) u16 sB[BN * BK];
    int tid = threadIdx.x;
    int wave = tid >> 6, lane = tid & 63;
    int wr = wave >> 1, wc = wave & 1;

    // XCD-aware block swizzle
    int bid = blockIdx.x;
    int G = nx * 8;
    int g = bid / G;
    int rem = ny - g * 8;
    int rb, cb;
    if (rem >= 8) {
        int r = bid - g * G;
        rb = g * 8 + (r & 7);
        cb = r >> 3;
    } else {
        int t = bid - g * G;
        rb = g * 8 + t % rem;
        cb = t / rem;
    }
    int m0 = rb * BM, n0 = cb * BN;

    int fm = lane & 15;
    int q = lane >> 4;

    int srow = lane >> 2;
    int sch = (lane & 3) * 8;
    u16* lA0 = &sA[(wave * 32) * BK];
    u16* lA1 = &sA[(wave * 32 + 16) * BK];
    u16* lB0 = &sB[(wave * 32) * BK];
    u16* lB1 = &sB[(wave * 32 + 16) * BK];
    int ar0 = min(m0 + wave * 32 + srow, M - 1);
    int ar1 = min(m0 + wave * 32 + 16 + srow, M - 1);
    int br0 = min(n0 + wave * 32 + srow, Ntot - 1);
    int br1 = min(n0 + wave * 32 + 16 + srow, Ntot - 1);

    float4v acc[4][4];
#pragma unroll
    for (int i = 0; i < 4; i++)
#pragma unroll
        for (int j = 0; j < 4; j++) acc[i][j] = (float4v){0.f, 0.f, 0.f, 0.f};

    for (int kc = 0; kc < K; kc += BK) {
        gload16(&A16[(size_t)ar0 * K + kc + sch], lA0);
        gload16(&A16[(size_t)ar1 * K + kc + sch], lA1);
        gload16(&BT[(size_t)br0 * K + kc + sch], lB0);
        gload16(&BT[(size_t)br1 * K + kc + sch], lB1);
        __syncthreads();

        half8 ah[4];
#pragma unroll
        for (int mi = 0; mi < 4; mi++)
            ah[mi] = *(const half8*)&sA[(wr * 64 + mi * 16 + fm) * BK + q * 8];
#pragma unroll
        for (int ni = 0; ni < 4; ni++) {
            half8 bh = *(const half8*)&sB[(wc * 64 + ni * 16 + fm) * BK + q * 8];
#pragma unroll
            for (int mi = 0; mi < 4; mi++)
                acc[mi][ni] = __builtin_amdgcn_mfma_f32_16x16x32_f16(ah[mi], bh, acc[mi][ni], 0, 0, 0);
        }
        __syncthreads();
    }

#pragma unroll
    for (int mi = 0; mi < 4; mi++) {
#pragma unroll
        for (int ni = 0; ni < 4; ni++) {
            int colg = n0 + wc * 64 + ni * 16 + fm;
            if (colg >= Ntot) continue;
            int cg = colg;
            if (pad121 && colg < Nb) {
                int hh = (colg * 1084) >> 17;   // colg/121 for colg<484
                cg = colg + 7 * hh;             // head*128 + class
            }
#pragma unroll
            for (int r = 0; r < 4; r++) {
                int rowg = m0 + wr * 64 + mi * 16 + q * 4 + r;
                if (rowg >= M) continue;
                float v = acc[mi][ni][r];
                if (colg < Nb) {
                    Cb[(size_t)rowg * strideB + cg] = f2h(v);
                } else {
                    int cf = colg - Nb;
                    Cf16[(size_t)rowg * strideF + cf] = f2h(v + biasf[cf]);
                }
            }
        }
    }
}

// ---------------- wave-per-node attention coefficients, C=64 (layers 1/2) ----------------
__global__ __launch_bounds__(256) void alpha_wave_256(const u16* __restrict__ xh,
                                                      const float* __restrict__ a_s,
                                                      const float* __restrict__ a_d,
                                                      float* __restrict__ as_o,
                                                      float* __restrict__ ad_o, int N) {
    int lane = threadIdx.x & 63;
    int n = blockIdx.x * 4 + (threadIdx.x >> 6);
    if (n >= N) return;
    int c = lane * 4;
    uint2 v = *(const uint2*)&xh[(size_t)n * HC12 + c];
    float4 s4 = *(const float4*)&a_s[c];
    float4 d4 = *(const float4*)&a_d[c];
    float x0 = h2f((u16)(v.x & 0xffff)), x1 = h2f((u16)(v.x >> 16));
    float x2 = h2f((u16)(v.y & 0xffff)), x3 = h2f((u16)(v.y >> 16));
    float ss = x0 * s4.x + x1 * s4.y + x2 * s4.z + x3 * s4.w;
    float sd = x0 * d4.x + x1 * d4.y + x2 * d4.z + x3 * d4.w;
#pragma unroll
    for (int o = 1; o < 16; o <<= 1) {
        ss += __shfl_xor(ss, o, 64);
        sd += __shfl_xor(sd, o, 64);
    }
    if ((lane & 15) == 0) {
        as_o[n * 4 + (lane >> 4)] = ss;
        ad_o[n * 4 + (lane >> 4)] = sd;
    }
}

// ---------------- wave-per-node layer-3 attention coefficients (padded, vectorized) ----------------
__global__ __launch_bounds__(256) void alpha3_wave(const u16* __restrict__ xh3,
                                                   const float* __restrict__ as3p,
                                                   const float* __restrict__ ad3p,
                                                   float* __restrict__ as_o,
                                                   float* __restrict__ ad_o, int N) {
    int l = threadIdx.x & 63;
    int n = blockIdx.x * 4 + (threadIdx.x >> 6);
    if (n >= N) return;
    int h = l >> 4, li = l & 15;
    int c0 = li * 8;
    uint4 v = *(const uint4*)&xh3[(size_t)n * HC3P + l * 8];
    float4 s0 = *(const float4*)&as3p[l * 8];
    float4 s1 = *(const float4*)&as3p[l * 8 + 4];
    float4 d0 = *(const float4*)&ad3p[l * 8];
    float4 d1 = *(const float4*)&ad3p[l * 8 + 4];
    u32 ww[4] = {v.x, v.y, v.z, v.w};
    float xs[8];
#pragma unroll
    for (int j = 0; j < 8; j++) {
        float xf = h2f((u16)((ww[j >> 1] >> ((j & 1) * 16)) & 0xffff));
        xs[j] = (c0 + j < NCLS) ? xf : 0.f;   // mask pad garbage (could be NaN)
    }
    float ss = xs[0] * s0.x + xs[1] * s0.y + xs[2] * s0.z + xs[3] * s0.w
             + xs[4] * s1.x + xs[5] * s1.y + xs[6] * s1.z + xs[7] * s1.w;
    float sd = xs[0] * d0.x + xs[1] * d0.y + xs[2] * d0.z + xs[3] * d0.w
             + xs[4] * d1.x + xs[5] * d1.y + xs[6] * d1.z + xs[7] * d1.w;
#pragma unroll
    for (int o = 1; o < 16; o <<= 1) {
        ss += __shfl_xor(ss, o, 64);
        sd += __shfl_xor(sd, o, 64);
    }
    if (li == 0) {
        as_o[n * 4 + h] = ss;
        ad_o[n * 4 + h] = sd;
    }
}

// ---------------- FUSED online-softmax aggregate, HC=256 (layers 1/2) ----------------
// Per 16-edge chunk: stats lanes (e_st=l>>2, hs=l&3) compute logits + chunk max/sum
// (online rescale, flash-style); gather lanes (s_slot=l>>5, li=l&31, 8 ch) accumulate
// alpha-tilde-weighted rows; divide by per-head running sum at the end.
__global__ __launch_bounds__(256) void agg_fused_256(const u16* __restrict__ xh,
                                                     const int* __restrict__ rowp,
                                                     const int* __restrict__ col,
                                                     const float* __restrict__ asrc,
                                                     const float* __restrict__ adst,
                                                     const float* __restrict__ bias,
                                                     const u16* __restrict__ res16,
                                                     u16* __restrict__ out16, int N) {
    int l = threadIdx.x & 63;
    int n = blockIdx.x * 4 + (threadIdx.x >> 6);
    if (n >= N) return;
    int r0 = rowp[n], r1 = rowp[n + 1];
    int s_slot = l >> 5, li = l & 31;
    int c = li * 8;
    int h = li >> 3;            // own head (gather role)
    int hs = l & 3;             // stats head
    int e_st = l >> 2;          // stats edge slot 0..15
    float ad = adst[n * 4 + hs];
    float m = -3.4e38f, ssum = 0.f;
    float acc[8] = {0.f, 0.f, 0.f, 0.f, 0.f, 0.f, 0.f, 0.f};
    for (int kb = r0; kb < r1; kb += 16) {
        int cn = min(16, r1 - kb);
        int cidx = col[kb + (l & 15)];
        // ---- stats phase (online softmax) ----
        int esc = __shfl(cidx, e_st, 64);
        bool ev = e_st < cn;
        float lg = ev ? lrelu(asrc[esc * 4 + hs] + ad) : -3.4e38f;
        float cm = lg;
#pragma unroll
        for (int o = 4; o < 64; o <<= 1) cm = fmaxf(cm, __shfl_xor(cm, o, 64));
        float mn = fmaxf(m, cm);
        float es = __expf(m - mn);
        float atil = ev ? __expf(lg - mn) : 0.f;
        float cs = atil;
#pragma unroll
        for (int o = 4; o < 64; o <<= 1) cs += __shfl_xor(cs, o, 64);
        ssum = ssum * es + cs;
        m = mn;
        float eso = __shfl(es, (l & 60) | h, 64);   // rescale for own head
#pragma unroll
        for (int j = 0; j < 8; j++) acc[j] *= eso;
        // ---- gather phase ----
        int npair = (cn + 1) >> 1;
#pragma unroll 4
        for (int k = 0; k < npair; k++) {
            int e = 2 * k + s_slot;
            int em = e < cn ? e : cn - 1;
            int src = __shfl(cidx, em, 64);
            float al = __shfl(atil, em * 4 + h, 64);
            if (e >= cn) al = 0.f;
            uint4 v = *(const uint4*)&xh[(size_t)src * HC12 + c];
            acc[0] += al * h2f((u16)(v.x & 0xffff));
            acc[1] += al * h2f((u16)(v.x >> 16));
            acc[2] += al * h2f((u16)(v.y & 0xffff));
            acc[3] += al * h2f((u16)(v.y >> 16));
            acc[4] += al * h2f((u16)(v.z & 0xffff));
            acc[5] += al * h2f((u16)(v.z >> 16));
            acc[6] += al * h2f((u16)(v.w & 0xffff));
            acc[7] += al * h2f((u16)(v.w >> 16));
        }
    }
    float sso = __shfl(ssum, (l & 60) | h, 64);
    float inv = 1.f / (sso + 1e-16f);
#pragma unroll
    for (int j = 0; j < 8; j++) acc[j] += __shfl_xor(acc[j], 32, 64);
    if (l < 32) {
        uint4 rv = *(const uint4*)&res16[(size_t)n * HC12 + c];
        u32 rw[4] = {rv.x, rv.y, rv.z, rv.w};
        float4 b0 = *(const float4*)&bias[c];
        float4 b1v = *(const float4*)&bias[c + 4];
        float bb[8] = {b0.x, b0.y, b0.z, b0.w, b1v.x, b1v.y, b1v.z, b1v.w};
        union { u16 u[8]; uint4 v; } p;
#pragma unroll
        for (int j = 0; j < 8; j++) {
            float rf = h2f((u16)((rw[j >> 1] >> ((j & 1) * 16)) & 0xffff));
            float vv = acc[j] * inv + bb[j] + rf;
            float ev2 = vv > 0.f ? vv : expm1f(vv);
            p.u[j] = f2h(ev2);
        }
        *(uint4*)&out16[(size_t)n * HC12 + c] = p.v;
    }
}

// ---------------- FUSED layer-3 aggregate: 2 nodes/wave, online softmax, no LDS ----------------
// Half-wave per node; 8-edge chunks; stats lanes (e_st=li>>2, hs=li&3) within the half.
// Per-head 1/s applied BEFORE the head-mean shfl reduce (heads have different denominators).
__global__ __launch_bounds__(256) void agg_fused_out(const u16* __restrict__ xh3,
                                                     const int* __restrict__ rowp,
                                                     const int* __restrict__ col,
                                                     const float* __restrict__ asrc,
                                                     const float* __restrict__ adst,
                                                     const float* __restrict__ b3,
                                                     const u16* __restrict__ lin3h,
                                                     float* __restrict__ out, int N) {
    int l = threadIdx.x & 63;
    int half = l >> 5, li = l & 31;
    int bl = l & 32;
    int n = blockIdx.x * 8 + (threadIdx.x >> 6) * 2 + half;
    bool nv = n < N;
    int r0 = nv ? rowp[n] : 0;
    int r1 = nv ? rowp[n + 1] : 0;
    int h = li >> 3;            // own head (gather role)
    int hs = li & 3;            // stats head
    int e_st = li >> 2;         // stats edge slot 0..7
    float ad = nv ? adst[n * 4 + hs] : 0.f;
    float m = -3.4e38f, ssum = 0.f;
    float acc[16];
#pragma unroll
    for (int j = 0; j < 16; j++) acc[j] = 0.f;
    for (int kb = r0; kb < r1; kb += 8) {
        int cn = min(8, r1 - kb);
        int ce = kb + (li & 7);
        int cidx = col[ce < r1 ? ce : r0];
        // ---- stats phase (within the half-wave) ----
        int esc = __shfl(cidx, bl + e_st, 64);
        bool ev = e_st < cn;
        float lg = ev ? lrelu(asrc[esc * 4 + hs] + ad) : -3.4e38f;
        float cm = lg;
#pragma unroll
        for (int o = 4; o < 32; o <<= 1) cm = fmaxf(cm, __shfl_xor(cm, o, 64));
        float mn = fmaxf(m, cm);
        float es = __expf(m - mn);
        float atil = ev ? __expf(lg - mn) : 0.f;
        float cs = atil;
#pragma unroll
        for (int o = 4; o < 32; o <<= 1) cs += __shfl_xor(cs, o, 64);
        ssum = ssum * es + cs;
        m = mn;
        float eso = __shfl(es, bl + ((li & 28) | h), 64);
#pragma unroll
        for (int j = 0; j < 16; j++) acc[j] *= eso;
        // ---- gather phase ----
        for (int k = 0; k < cn; k++) {
            int src = __shfl(cidx, bl + k, 64);
            float al = __shfl(atil, bl + k * 4 + h, 64);
            const u16* row = xh3 + (size_t)src * HC3P + li * 16;
            uint4 v0 = *(const uint4*)&row[0];
            uint4 v1 = *(const uint4*)&row[8];
            u32 w0[4] = {v0.x, v0.y, v0.z, v0.w};
            u32 w1[4] = {v1.x, v1.y, v1.z, v1.w};
#pragma unroll
            for (int jj = 0; jj < 4; jj++) {
                acc[2 * jj]     += al * h2f((u16)(w0[jj] & 0xffff));
                acc[2 * jj + 1] += al * h2f((u16)(w0[jj] >> 16));
                acc[8 + 2 * jj]     += al * h2f((u16)(w1[jj] & 0xffff));
                acc[8 + 2 * jj + 1] += al * h2f((u16)(w1[jj] >> 16));
            }
        }
    }
    // per-head normalize BEFORE head-mean
    float sso = __shfl(ssum, bl + ((li & 28) | h), 64);
    float inv = 1.f / (sso + 1e-16f);
#pragma unroll
    for (int j = 0; j < 16; j++) acc[j] *= inv;
    // head-mean: xor 8 flips head bit0, xor 16 flips head bit1 (class block li&7 preserved)
#pragma unroll
    for (int j = 0; j < 16; j++) {
        acc[j] += __shfl_xor(acc[j], 8, 64);
        acc[j] += __shfl_xor(acc[j], 16, 64);
    }
    if (nv && li < 8) {
        int c0 = li * 16;
        uint4 l0 = *(const uint4*)&lin3h[(size_t)n * L3STR + c0];
        uint4 l1 = *(const uint4*)&lin3h[(size_t)n * L3STR + c0 + 8];
        u32 lw[8] = {l0.x, l0.y, l0.z, l0.w, l1.x, l1.y, l1.z, l1.w};
#pragma unroll
        for (int j = 0; j < 16; j++) {
            int cc = c0 + j;
            if (cc < NCLS) {
                float lf = h2f((u16)((lw[j >> 1] >> ((j & 1) * 16)) & 0xffff));
                out[(size_t)n * NCLS + cc] = 0.25f * acc[j] + b3[cc] + lf;
            }
        }
    }
}

extern "C" void kernel_launch(void* const* d_in, const int* in_sizes, int n_in,
                              void* d_out, int out_size, void* d_ws, size_t ws_size,
                              hipStream_t stream) {
    const float* x   = (const float*)d_in[0];
    const int*   ei  = (const int*)d_in[1];
    const float* W1  = (const float*)d_in[2];
    const float* a1s = (const float*)d_in[3];
    const float* a1d = (const float*)d_in[4];
    const float* b1  = (const float*)d_in[5];
    const float* l1W = (const float*)d_in[6];
    const float* l1b = (const float*)d_in[7];
    const float* W2  = (const float*)d_in[8];
    const float* a2s = (const float*)d_in[9];
    const float* a2d = (const float*)d_in[10];
    const float* b2  = (const float*)d_in[11];
    const float* W3  = (const float*)d_in[12];
    const float* a3s = (const float*)d_in[13];
    const float* a3d = (const float*)d_in[14];
    const float* b3  = (const float*)d_in[15];
    const float* l3W = (const float*)d_in[16];
    const float* l3b = (const float*)d_in[17];

    const int N = in_sizes[0] / F_IN;   // 50000
    const int E = in_sizes[1] / 2;      // 400000
    const int* srcv = ei;
    const int* dstv = ei + E;

    char* ws = (char*)d_ws;
    size_t off = 0;
    auto alloc = [&](size_t bytes) -> char* {
        char* p = ws + off;
        off += (bytes + 255) & ~(size_t)255;
        return p;
    };
    u16*   xh    = (u16*)alloc((size_t)N * HC3P * 2 + 256);
    u16*   x16   = (u16*)alloc((size_t)N * F_IN * 2);
    u16*   h1f   = (u16*)alloc((size_t)N * HC12 * 2);
    u16*   h2f   = (u16*)alloc((size_t)N * HC12 * 2);
    u16*   lin1h = (u16*)alloc((size_t)N * HC12 * 2);
    u16*   lin3h = (u16*)alloc((size_t)N * L3STR * 2);
    float* as_   = (float*)alloc((size_t)N * 4 * 4);
    float* ad_   = (float*)alloc((size_t)N * 4 * 4);
    int* rowp    = (int*)alloc((size_t)(N + 1) * 4);
    int* degc    = (int*)alloc((size_t)N * 4);
    int* cur     = (int*)alloc((size_t)N * 4);
    int* part    = (int*)alloc((size_t)256 * 4);
    int* col     = (int*)alloc((size_t)E * 4 + 256);
    u16* C1 = (u16*)alloc((size_t)512 * 128 * 2);
    u16* C2 = (u16*)alloc((size_t)256 * 256 * 2);
    u16* C3 = (u16*)alloc((size_t)605 * 256 * 2);
    float* as3p = (float*)alloc(512 * 4);
    float* ad3p = (float*)alloc(512 * 4);
    (void)ws_size; (void)n_in; (void)out_size;

    // ---- CSR build (parallel scan) ----
    hipMemsetAsync(degc, 0, (size_t)N * 4, stream);
    hipMemsetAsync(cur, 0, (size_t)N * 4, stream);
    hist_kernel<<<(E + 255) / 256, 256, 0, stream>>>(dstv, degc, E);
    int nb = (N + 1023) / 1024;
    scan_part<<<nb, 256, 0, stream>>>(degc, part, N);
    scan_mid<<<1, 64, 0, stream>>>(part, nb);
    scan_final<<<nb, 256, 0, stream>>>(degc, part, rowp, N);
    scatter_kernel<<<(E + 255) / 256, 256, 0, stream>>>(srcv, dstv, rowp, cur, col, E);

    // ---- weight transpose + x conversion + padded a3 tables ----
    cvtT_all_kernel<<<(285952 + 1024 + 255) / 256, 256, 0, stream>>>(W1, l1W, W2, W3, l3W,
                                                                     a3s, a3d, C1, C2, C3,
                                                                     as3p, ad3p);
    xcvt_kernel<<<(N * F_IN / 8 + 255) / 256, 256, 0, stream>>>(x, x16, N * F_IN / 8);

    int ny = (N + BM - 1) / BM;
    int wgrid = (N + 3) / 4;
    int wgrid8 = (N + 7) / 8;

    // ---- layer 1: one GEMM, N=512 (cols 0-255 -> xh f16, 256-511 -> lin1h f16 + l1b) ----
    gemm_f16<<<4 * ny, 256, 0, stream>>>(x16, C1, N, F_IN, 512, 4, ny,
                                         256, xh, 256, 0, lin1h, l1b, 256);
    alpha_wave_256<<<wgrid, 256, 0, stream>>>(xh, a1s, a1d, as_, ad_, N);
    agg_fused_256<<<wgrid, 256, 0, stream>>>(xh, rowp, col, as_, ad_, b1, lin1h, h1f, N);

    // ---- layer 2: N=256, residual = h1f ----
    gemm_f16<<<2 * ny, 256, 0, stream>>>(h1f, C2, N, HC12, 256, 2, ny,
                                         256, xh, 256, 0, nullptr, nullptr, 0);
    alpha_wave_256<<<wgrid, 256, 0, stream>>>(xh, a2s, a2d, as_, ad_, N);
    agg_fused_256<<<wgrid, 256, 0, stream>>>(xh, rowp, col, as_, ad_, b2, h1f, h2f, N);

    // ---- layer 3: one GEMM, N=605, padded xh3 (stride 512), cols 484-604 -> lin3h f16 + l3b ----
    gemm_f16<<<5 * ny, 256, 0, stream>>>(h2f, C3, N, HC12, 605, 5, ny,
                                         484, xh, HC3P, 1, lin3h, l3b, L3STR);
    alpha3_wave<<<wgrid, 256, 0, stream>>>(xh, as3p, ad3p, as_, ad_, N);
    agg_fused_out<<<wgrid8, 256, 0, stream>>>(xh, rowp, col, as_, ad_, b3, lin3h,
                                              (float*)d_out, N);
}